// Round 2
// baseline (17757.054 us; speedup 1.0000x reference)
//
#include <hip/hip_runtime.h>
#include <hip/hip_bf16.h>
#include <math.h>

// Problem constants (fixed by setup_inputs)
#define Bb   32
#define Ll   30
#define Hh   300
#define Pp   8
#define Nn   16384
#define Ee   131072
#define NPG  512     // nodes per graph (node_indices = n/512)
#define NI   5       // N_INSTR

__device__ __forceinline__ float eluf(float x){ return x > 0.f ? x : expm1f(x); }
__device__ __forceinline__ float sigf(float x){ return 1.f/(1.f+expf(-x)); }
__device__ __forceinline__ float wave_sum(float s){
    s += __shfl_xor(s, 32); s += __shfl_xor(s, 16); s += __shfl_xor(s, 8);
    s += __shfl_xor(s, 4);  s += __shfl_xor(s, 2);  s += __shfl_xor(s, 1);
    return s;
}

// ---------------------------------------------------------------------------
// Tiled f32 GEMM: 32 rows x 320 cols per block, 128 threads, 4x20 per thread.
// C[M,N] = A'[M,K] @ B      (A'[m,k] = A[m,k] * S[rowb[m], k] if ASCALE)
// BT=false: B is (K,N) row-major.  BT=true: B is (N,K) row-major (A @ B^T).
// EPI 0: write C (f32, ldc=N)
// EPI 1: out[m] = sum_c elu(C[m,c]) * w[c]   (fused node/edge score epilogue)
// ---------------------------------------------------------------------------
template<bool BT, bool ASCALE, int EPI>
__global__ __launch_bounds__(128) void gemm_k(
    const float* __restrict__ A, int lda, int M, int K,
    const float* __restrict__ Bm, int N,
    const float* __restrict__ S, int sstride, const int* __restrict__ rowb,
    const float* __restrict__ w,
    float* __restrict__ Cf)
{
    __shared__ __align__(16) float As[16*36];   // [k][row], stride 36
    __shared__ __align__(16) float Bs[16*324];  // [k][col], stride 324
    __shared__ float red[16][32];

    const int t  = threadIdx.x;
    const int tr = t & 7;          // row group (4 rows each)
    const int tc = t >> 3;         // col group (20 cols each)
    const int rowBlock = blockIdx.x * 32;
    const int colBase  = blockIdx.y * 320;

    float acc[4][20];
    #pragma unroll
    for (int r = 0; r < 4; r++){
        #pragma unroll
        for (int c = 0; c < 20; c++) acc[r][c] = 0.f;
    }

    const int ar = rowBlock + (t >> 2);   // staging row for this thread
    const int kc = (t & 3) * 4;           // staging k sub-offset
    int bb = 0;
    if (ASCALE && ar < M) bb = rowb[ar];

    const int numT = (K + 15) >> 4;
    for (int kt = 0; kt < numT; ++kt) {
        const int k0 = kt << 4;
        // ---- stage A (with optional per-element scale) ----
        #pragma unroll
        for (int j = 0; j < 4; j++){
            int kk = k0 + kc + j;
            float x = 0.f;
            if (ar < M && kk < K) {
                x = A[(size_t)ar * lda + kk];
                if (ASCALE) x *= S[(size_t)bb * sstride + kk];
            }
            As[(kc + j) * 36 + (t >> 2)] = x;
        }
        // ---- stage B ----
        if (!BT) {
            #pragma unroll
            for (int i = 0; i < 40; i++){
                int idx = i * 128 + t;          // < 5120
                int k = idx / 320;
                int c = idx - k * 320;
                int gk = k0 + k, gc = colBase + c;
                float v = 0.f;
                if (gk < K && gc < N) v = Bm[(size_t)gk * N + gc];
                Bs[k * 324 + c] = v;
            }
        } else {
            #pragma unroll
            for (int i = 0; i < 40; i++){
                int idx = i * 128 + t;
                int k = idx & 15;
                int c = idx >> 4;
                int gk = k0 + k, gc = colBase + c;
                float v = 0.f;
                if (gk < K && gc < N) v = Bm[(size_t)gc * K + gk];
                Bs[k * 324 + c] = v;
            }
        }
        __syncthreads();
        // ---- inner product ----
        #pragma unroll
        for (int kk = 0; kk < 16; ++kk){
            float4 a4 = *(const float4*)&As[kk * 36 + tr * 4];
            float av[4] = {a4.x, a4.y, a4.z, a4.w};
            float bv[20];
            #pragma unroll
            for (int j = 0; j < 5; j++){
                float4 b4 = *(const float4*)&Bs[kk * 324 + tc * 20 + j * 4];
                bv[j*4+0] = b4.x; bv[j*4+1] = b4.y; bv[j*4+2] = b4.z; bv[j*4+3] = b4.w;
            }
            #pragma unroll
            for (int r = 0; r < 4; r++){
                #pragma unroll
                for (int c = 0; c < 20; c++)
                    acc[r][c] = fmaf(av[r], bv[c], acc[r][c]);
            }
        }
        __syncthreads();
    }

    if (EPI == 1) {
        #pragma unroll
        for (int r = 0; r < 4; r++){
            float p = 0.f;
            #pragma unroll
            for (int c = 0; c < 20; c++){
                int col = colBase + tc * 20 + c;
                if (col < N) p += eluf(acc[r][c]) * w[col];
            }
            red[tc][tr * 4 + r] = p;
        }
        __syncthreads();
        if (t < 32) {
            float s = 0.f;
            #pragma unroll
            for (int j = 0; j < 16; j++) s += red[j][t];
            int row = rowBlock + t;
            if (row < M) Cf[row] = s;
        }
    } else {
        #pragma unroll
        for (int r = 0; r < 4; r++){
            int row = rowBlock + tr * 4 + r;
            if (row >= M) continue;
            #pragma unroll
            for (int c = 0; c < 20; c++){
                int col = colBase + tc * 20 + c;
                if (col >= N) continue;
                Cf[(size_t)row * N + col] = acc[r][c];
            }
        }
    }
}

// Naive thread-per-output A @ B^T for tiny-M GEMMs (M=32).
// EPI 0: f32; 2: elu(x+bias) f32; 3: (x+bias) f32 (final output).
template<int EPI>
__global__ void mm_naive_bt_k(const float* __restrict__ A, int lda, int M, int K,
                              const float* __restrict__ Bm, int N,
                              const float* __restrict__ bias,
                              float* __restrict__ Cf)
{
    int idx = blockIdx.x * 256 + threadIdx.x;
    if (idx >= M * N) return;
    int m = idx / N;
    int j = idx - m * N;
    const float* arow = A + (size_t)m * lda;
    const float* brow = Bm + (size_t)j * K;
    float s = 0.f;
    for (int k = 0; k < K; k++) s += arow[k] * brow[k];
    if (EPI == 0) Cf[idx] = s;
    else if (EPI == 2) Cf[idx] = eluf(s + bias[j]);
    else Cf[idx] = s + bias[j];
}

// ---------------------------------------------------------------------------
__global__ void vocab_build_k(const float* __restrict__ cv, const float* __restrict__ td,
                              float* __restrict__ ve)
{
    int idx = blockIdx.x * 256 + threadIdx.x;
    if (idx < 2001 * 300) ve[idx] = (idx < 2000 * 300) ? cv[idx] : td[idx - 2000 * 300];
}

__global__ void softmax_rows_k(float* __restrict__ X, int nc)
{
    int row = blockIdx.x, t = threadIdx.x;
    __shared__ float red[256];
    size_t base = (size_t)row * nc;
    float m = -3.4e38f;
    for (int i = t; i < nc; i += 256) m = fmaxf(m, X[base + i]);
    red[t] = m; __syncthreads();
    for (int s = 128; s > 0; s >>= 1){ if (t < s) red[t] = fmaxf(red[t], red[t+s]); __syncthreads(); }
    float mx = red[0]; __syncthreads();
    float sm = 0.f;
    for (int i = t; i < nc; i += 256){ float e = expf(X[base + i] - mx); X[base + i] = e; sm += e; }
    red[t] = sm; __syncthreads();
    for (int s = 128; s > 0; s >>= 1){ if (t < s) red[t] += red[t+s]; __syncthreads(); }
    float inv = 1.f / red[0];
    for (int i = t; i < nc; i += 256) X[base + i] *= inv;
}

__global__ void tagged_add_k(const float* __restrict__ sim, const float* __restrict__ q,
                             float* __restrict__ tg)
{
    int idx = blockIdx.x * 256 + threadIdx.x;
    if (idx >= 960 * 300) return;
    int row = idx / 300;
    tg[idx] += sim[(size_t)row * 2001 + 2000] * q[idx];
}

__global__ __launch_bounds__(256) void lstm_step_k(
    const float* __restrict__ xW, const float* __restrict__ Whh,
    const float* __restrict__ bih, const float* __restrict__ bhh,
    const float* __restrict__ h_in, const float* __restrict__ c_in,
    float* __restrict__ h_out, float* __restrict__ c_out,
    const int* __restrict__ lengths, int t)
{
    int wid = blockIdx.x * 4 + (threadIdx.x >> 6);   // 0..9599
    int lane = threadIdx.x & 63;
    int b = wid / Hh, hid = wid - b * Hh;
    float hv[5];
    #pragma unroll
    for (int p = 0; p < 5; p++){ int k = lane + p * 64; hv[p] = (k < Hh) ? h_in[b * Hh + k] : 0.f; }
    float d[4];
    #pragma unroll
    for (int g = 0; g < 4; g++){
        const float* wr = Whh + (size_t)(g * Hh + hid) * Hh;
        float s = 0.f;
        #pragma unroll
        for (int p = 0; p < 5; p++){ int k = lane + p * 64; if (k < Hh) s += hv[p] * wr[k]; }
        d[g] = wave_sum(s);
    }
    if (lane == 0){
        const float* xr = xW + (size_t)(b * Ll + t) * 1200;
        float i_ = sigf (xr[hid]       + bih[hid]       + bhh[hid]       + d[0]);
        float f_ = sigf (xr[300 + hid] + bih[300 + hid] + bhh[300 + hid] + d[1]);
        float g_ = tanhf(xr[600 + hid] + bih[600 + hid] + bhh[600 + hid] + d[2]);
        float o_ = sigf (xr[900 + hid] + bih[900 + hid] + bhh[900 + hid] + d[3]);
        float cn = f_ * c_in[b * Hh + hid] + i_ * g_;
        float hn = o_ * tanhf(cn);
        bool msk = t < lengths[b];
        h_out[b * Hh + hid] = msk ? hn : h_in[b * Hh + hid];
        c_out[b * Hh + hid] = msk ? cn : c_in[b * Hh + hid];
    }
}

__global__ __launch_bounds__(256) void rnn_iter_k(
    const float* __restrict__ exG, const float* __restrict__ Whh,
    const float* __restrict__ bih, const float* __restrict__ bhh,
    const float* __restrict__ hx_in, float* __restrict__ hx_out,
    float* __restrict__ hidden, int it)
{
    int wid = blockIdx.x * 4 + (threadIdx.x >> 6);
    int lane = threadIdx.x & 63;
    int b = wid / Hh, hid = wid - b * Hh;
    const float* wr = Whh + (size_t)hid * Hh;
    float s = 0.f;
    #pragma unroll
    for (int p = 0; p < 5; p++){ int k = lane + p * 64; if (k < Hh) s += hx_in[b * Hh + k] * wr[k]; }
    s = wave_sum(s);
    if (lane == 0){
        float v = exG[b * Hh + hid] + bih[hid] + bhh[hid] + s;
        v = fmaxf(v, 0.f);
        hx_out[b * Hh + hid] = v;
        hidden[((size_t)b * NI + it) * Hh + hid] = v;
    }
}

__global__ __launch_bounds__(256) void scores_instr_k(
    const float* __restrict__ hidden, const float* __restrict__ tagged,
    const int* __restrict__ lengths, float* __restrict__ instr)
{
    __shared__ float sc[4][32];
    int wv = threadIdx.x >> 6;
    int wid = blockIdx.x * 4 + wv;          // 0..159 == b*5+i
    int lane = threadIdx.x & 63;
    int b = wid / NI;
    const float* hr = hidden + (size_t)wid * Hh;
    float hv[5];
    #pragma unroll
    for (int p = 0; p < 5; p++){ int k = lane + p * 64; hv[p] = (k < Hh) ? hr[k] : 0.f; }
    int len = lengths[b];
    for (int l = 0; l < Ll; l++){
        const float* trw = tagged + ((size_t)b * Ll + l) * Hh;
        float s = 0.f;
        #pragma unroll
        for (int p = 0; p < 5; p++){ int k = lane + p * 64; if (k < Hh) s += hv[p] * trw[k]; }
        s = wave_sum(s);
        if (lane == 0) sc[wv][l] = s;
    }
    __syncthreads();
    float mx = -3.4e38f;
    for (int l = 0; l < len; l++) mx = fmaxf(mx, sc[wv][l]);
    float sum = 0.f;
    for (int l = 0; l < len; l++) sum += expf(sc[wv][l] - mx);
    float inv = 1.f / sum;
    float a[5] = {0.f,0.f,0.f,0.f,0.f};
    for (int l = 0; l < len; l++){
        float pl = expf(sc[wv][l] - mx) * inv;
        const float* trw = tagged + ((size_t)b * Ll + l) * Hh;
        #pragma unroll
        for (int p = 0; p < 5; p++){ int k = lane + p * 64; if (k < Hh) a[p] += pl * trw[k]; }
    }
    #pragma unroll
    for (int p = 0; p < 5; p++){ int k = lane + p * 64; if (k < Hh) instr[(size_t)wid * Hh + k] = a[p]; }
}

__global__ __launch_bounds__(256) void prop_softmax_k(
    const float* __restrict__ instr, int ii, const float* __restrict__ pemb,
    float* __restrict__ psim, float* __restrict__ rsim)
{
    int wid = blockIdx.x * 4 + (threadIdx.x >> 6);   // b, 0..31
    int lane = threadIdx.x & 63;
    const float* ir = instr + ((size_t)wid * NI + ii) * Hh;
    float iv[5];
    #pragma unroll
    for (int p = 0; p < 5; p++){ int k = lane + p * 64; iv[p] = (k < Hh) ? ir[k] : 0.f; }
    float e[9];
    #pragma unroll
    for (int j = 0; j < 9; j++){
        const float* pr = pemb + j * Hh;
        float s = 0.f;
        #pragma unroll
        for (int p = 0; p < 5; p++){ int k = lane + p * 64; if (k < Hh) s += iv[p] * pr[k]; }
        e[j] = wave_sum(s);
    }
    if (lane == 0){
        float mx = e[0];
        #pragma unroll
        for (int j = 1; j < 9; j++) mx = fmaxf(mx, e[j]);
        float sum = 0.f;
        #pragma unroll
        for (int j = 0; j < 9; j++){ e[j] = expf(e[j] - mx); sum += e[j]; }
        float inv = 1.f / sum;
        #pragma unroll
        for (int p = 0; p < 8; p++) psim[wid * 8 + p] = e[p] * inv;
        rsim[wid] = e[8] * inv;
    }
}

__global__ void iscale_k(const float* __restrict__ instr, int step,
                         const float* __restrict__ psim, float* __restrict__ iscale)
{
    int idx = blockIdx.x * 256 + threadIdx.x;      // < 32*2400
    if (idx >= Bb * 2400) return;
    int b = idx / 2400; int k = idx - b * 2400;
    int p = k / 300;    int h = k - p * 300;
    iscale[idx] = instr[((size_t)b * NI + step) * Hh + h] * psim[b * 8 + p];
}

__global__ void count_k(const int* __restrict__ ni, int* __restrict__ cnt)
{
    int n = blockIdx.x * 256 + threadIdx.x;
    if (n < Nn) atomicAdd(&cnt[ni[n]], 1);
}
__global__ void dist_init_k(const int* __restrict__ ni, const int* __restrict__ cnt,
                            float* __restrict__ dist)
{
    int n = blockIdx.x * 256 + threadIdx.x;
    if (n < Nn) dist[n] = 1.f / (float)cnt[ni[n]];
}

__global__ void edge_msg_k(const int* __restrict__ ei, const float* __restrict__ es,
                           const float* __restrict__ dist, float* __restrict__ msgdot)
{
    int e = blockIdx.x * 256 + threadIdx.x;
    if (e < Ee){
        int s = ei[e];
        int d = ei[Ee + e];
        atomicAdd(&msgdot[d], dist[s] * es[e]);
    }
}

__global__ __launch_bounds__(256) void seg_update_k(
    const float* __restrict__ nscore, const float* __restrict__ msgdot,
    const float* __restrict__ rsim, float* __restrict__ dist)
{
    int b = blockIdx.x, t = threadIdx.x;
    __shared__ float red[256];
    int n0 = b * NPG;
    float a1 = nscore[n0 + t], a2 = nscore[n0 + 256 + t];
    float m1 = msgdot[n0 + t], m2 = msgdot[n0 + 256 + t];

    red[t] = fmaxf(a1, a2); __syncthreads();
    for (int s = 128; s > 0; s >>= 1){ if (t < s) red[t] = fmaxf(red[t], red[t+s]); __syncthreads(); }
    float mN = red[0]; __syncthreads();
    float e1 = expf(a1 - mN), e2 = expf(a2 - mN);
    red[t] = e1 + e2; __syncthreads();
    for (int s = 128; s > 0; s >>= 1){ if (t < s) red[t] += red[t+s]; __syncthreads(); }
    float sN = red[0]; __syncthreads();

    red[t] = fmaxf(m1, m2); __syncthreads();
    for (int s = 128; s > 0; s >>= 1){ if (t < s) red[t] = fmaxf(red[t], red[t+s]); __syncthreads(); }
    float mM = red[0]; __syncthreads();
    float f1 = expf(m1 - mM), f2 = expf(m2 - mM);
    red[t] = f1 + f2; __syncthreads();
    for (int s = 128; s > 0; s >>= 1){ if (t < s) red[t] += red[t+s]; __syncthreads(); }
    float sM = red[0];

    float rs = rsim[b];
    dist[n0 + t]       = rs * (f1 / sM) + (1.f - rs) * (e1 / sN);
    dist[n0 + 256 + t] = rs * (f2 / sM) + (1.f - rs) * (e2 / sN);
}

__global__ __launch_bounds__(320) void final_agg_k(
    const float* __restrict__ psim, const float* __restrict__ dist,
    const float* __restrict__ na, float* __restrict__ agg)
{
    int chunk = blockIdx.x;   // 0..15
    int b = blockIdx.y;       // 0..31
    int h = threadIdx.x;
    if (h >= Hh) return;
    float ps[8];
    #pragma unroll
    for (int p = 0; p < 8; p++) ps[p] = psim[b * 8 + p];
    float acc = 0.f;
    for (int i = 0; i < 32; i++){
        int n = b * NPG + chunk * 32 + i;
        const float* row = na + (size_t)n * Pp * Hh;
        float wsum = 0.f;
        #pragma unroll
        for (int p = 0; p < 8; p++) wsum += ps[p] * row[p * Hh + h];
        acc += dist[n] * wsum;
    }
    atomicAdd(&agg[b * Hh + h], acc);
}

__global__ void feats_k(const float* __restrict__ enc, const float* __restrict__ agg,
                        float* __restrict__ feats)
{
    int idx = blockIdx.x * 256 + threadIdx.x;
    if (idx >= Bb * 600) return;
    int b = idx / 600, j = idx - b * 600;
    feats[idx] = (j < 300) ? enc[b * 300 + j] : agg[b * 300 + (j - 300)];
}

// ---------------------------------------------------------------------------
extern "C" void kernel_launch(void* const* d_in, const int* in_sizes, int n_in,
                              void* d_out, int out_size, void* d_ws, size_t ws_size,
                              hipStream_t stream)
{
    const float* questions      = (const float*)d_in[0];
    const int*   lengths        = (const int*)  d_in[1];
    const int*   node_indices   = (const int*)  d_in[2];
    const int*   edge_indices   = (const int*)  d_in[3];
    const int*   edge_batch     = (const int*)  d_in[4];
    const float* node_attrs     = (const float*)d_in[5];
    const float* edge_attrs     = (const float*)d_in[6];
    const float* concept_vocab  = (const float*)d_in[7];
    const float* prop_emb       = (const float*)d_in[8];
    const float* tagger_default = (const float*)d_in[9];
    const float* tagger_weight  = (const float*)d_in[10];
    const float* lstm_Wih       = (const float*)d_in[11];
    const float* lstm_Whh       = (const float*)d_in[12];
    const float* lstm_bih       = (const float*)d_in[13];
    const float* lstm_bhh       = (const float*)d_in[14];
    const float* rnn_Wih        = (const float*)d_in[15];
    const float* rnn_Whh        = (const float*)d_in[16];
    const float* rnn_bih        = (const float*)d_in[17];
    const float* rnn_bhh        = (const float*)d_in[18];
    const float* Wnp            = (const float*)d_in[19];
    const float* Wedge          = (const float*)d_in[20];
    const float* w_nscore       = (const float*)d_in[21];
    const float* w_rscore       = (const float*)d_in[22];
    const float* fc1_W          = (const float*)d_in[23];
    const float* fc1_b          = (const float*)d_in[24];
    const float* fc2_W          = (const float*)d_in[25];
    const float* fc2_b          = (const float*)d_in[26];
    float* outf = (float*)d_out;   // reference output dtype is float32

    float* ws = (float*)d_ws;
    size_t off = 0;
    auto alloc = [&](size_t n){ size_t r = off; off += (n + 63) & ~(size_t)63; return r; };
    size_t o_vocab  = alloc(2001 * 300);
    size_t o_q2     = alloc(960 * 300);
    size_t o_sim    = alloc((size_t)960 * 2001);
    size_t o_tagged = alloc(960 * 300);
    size_t o_xw     = alloc((size_t)960 * 1200);
    size_t o_h0     = alloc(9600);
    size_t o_c0     = alloc(9600);     // contiguous with h0 (both 64-aligned sizes)
    size_t o_h1     = alloc(9600);
    size_t o_c1     = alloc(9600);
    size_t o_exg    = alloc(9600);
    size_t o_hx0    = alloc(9600);
    size_t o_hx1    = alloc(9600);
    size_t o_hidden = alloc(48000);
    size_t o_instr  = alloc(48000);
    size_t o_psim   = alloc(256);
    size_t o_rsim   = alloc(64);
    size_t o_iscale = alloc((size_t)Bb * 2400);
    size_t o_nscore = alloc(Nn);
    size_t o_es     = alloc(Ee);
    size_t o_msgdot = alloc(Nn);
    size_t o_dist   = alloc(Nn);
    size_t o_cnt    = alloc(64);       // int counts
    size_t o_agg    = alloc(9600);
    size_t o_feats  = alloc(19200);
    size_t o_z      = alloc(19200);
    // total ~18.9 MB of ws

    // ---- tagger: vocab_ext, logits, softmax, tagged ----
    vocab_build_k<<<(2001*300 + 255)/256, 256, 0, stream>>>(concept_vocab, tagger_default, ws + o_vocab);
    // q2 = questions @ tagger_weight   (B non-transposed, (K,N) layout)
    gemm_k<false,false,0><<<dim3(30,1), 128, 0, stream>>>(
        questions, 300, 960, 300, tagger_weight, 300, nullptr, 0, nullptr, nullptr, ws + o_q2);
    // logits = q2 @ vocab_ext^T
    gemm_k<true,false,0><<<dim3(30,7), 128, 0, stream>>>(
        ws + o_q2, 300, 960, 300, ws + o_vocab, 2001, nullptr, 0, nullptr, nullptr, ws + o_sim);
    softmax_rows_k<<<960, 256, 0, stream>>>(ws + o_sim, 2001);
    // tagged = sim[:, :2000] @ concept_vocab
    gemm_k<false,false,0><<<dim3(30,1), 128, 0, stream>>>(
        ws + o_sim, 2001, 960, 2000, concept_vocab, 300, nullptr, 0, nullptr, nullptr, ws + o_tagged);
    tagged_add_k<<<1125, 256, 0, stream>>>(ws + o_sim, questions, ws + o_tagged);

    // ---- LSTM ----
    // xW = tagged @ lstm_Wih^T
    gemm_k<true,false,0><<<dim3(30,4), 128, 0, stream>>>(
        ws + o_tagged, 300, 960, 300, lstm_Wih, 1200, nullptr, 0, nullptr, nullptr, ws + o_xw);
    hipMemsetAsync(ws + o_h0, 0, 2 * 9600 * sizeof(float), stream);   // h0 and c0
    float* hbuf[2] = {ws + o_h0, ws + o_h1};
    float* cbuf[2] = {ws + o_c0, ws + o_c1};
    for (int t = 0; t < Ll; t++){
        int a = t & 1, b2 = 1 - a;
        lstm_step_k<<<2400, 256, 0, stream>>>(ws + o_xw, lstm_Whh, lstm_bih, lstm_bhh,
            hbuf[a], cbuf[a], hbuf[b2], cbuf[b2], lengths, t);
    }
    const float* encoded = ws + o_h0;   // 30 steps -> ends back in buffer 0

    // ---- RNN instruction decoder ----
    mm_naive_bt_k<0><<<(9600 + 255)/256, 256, 0, stream>>>(
        encoded, 300, 32, 300, rnn_Wih, 300, nullptr, ws + o_exg);
    hipMemsetAsync(ws + o_hx0, 0, 9600 * sizeof(float), stream);
    float* hxb[2] = {ws + o_hx0, ws + o_hx1};
    for (int it = 0; it < NI; it++){
        int a = it & 1;
        rnn_iter_k<<<2400, 256, 0, stream>>>(ws + o_exg, rnn_Whh, rnn_bih, rnn_bhh,
            hxb[a], hxb[1 - a], ws + o_hidden, it);
    }
    scores_instr_k<<<40, 256, 0, stream>>>(ws + o_hidden, ws + o_tagged, lengths, ws + o_instr);

    // ---- distribution init ----
    hipMemsetAsync(ws + o_cnt, 0, 32 * sizeof(int), stream);
    count_k<<<64, 256, 0, stream>>>(node_indices, (int*)(ws + o_cnt));
    dist_init_k<<<64, 256, 0, stream>>>(node_indices, (int*)(ws + o_cnt), ws + o_dist);

    // ---- 4 message-passing steps ----
    for (int step = 0; step < 4; step++){
        prop_softmax_k<<<8, 256, 0, stream>>>(ws + o_instr, step, prop_emb, ws + o_psim, ws + o_rsim);
        iscale_k<<<300, 256, 0, stream>>>(ws + o_instr, step, ws + o_psim, ws + o_iscale);
        // node scores: (16384 x 2400) @ Wnp_flat(2400 x 300), fused elu-dot-w epilogue
        gemm_k<false,true,1><<<dim3(512,1), 128, 0, stream>>>(
            node_attrs, 2400, Nn, 2400, Wnp, 300,
            ws + o_iscale, 2400, node_indices, w_nscore, ws + o_nscore);
        // edge scores: (131072 x 300) @ Wedge(300 x 300), A scaled by instr[batch]
        gemm_k<false,true,1><<<dim3(4096,1), 128, 0, stream>>>(
            edge_attrs, 300, Ee, 300, Wedge, 300,
            ws + o_instr + step * 300, NI * 300, edge_batch, w_rscore, ws + o_es);
        hipMemsetAsync(ws + o_msgdot, 0, Nn * sizeof(float), stream);
        edge_msg_k<<<512, 256, 0, stream>>>(edge_indices, ws + o_es, ws + o_dist, ws + o_msgdot);
        seg_update_k<<<32, 256, 0, stream>>>(ws + o_nscore, ws + o_msgdot, ws + o_rsim, ws + o_dist);
    }

    // ---- final aggregation + FCs ----
    prop_softmax_k<<<8, 256, 0, stream>>>(ws + o_instr, 4, prop_emb, ws + o_psim, ws + o_rsim);
    hipMemsetAsync(ws + o_agg, 0, 9600 * sizeof(float), stream);
    final_agg_k<<<dim3(16,32), 320, 0, stream>>>(ws + o_psim, ws + o_dist, node_attrs, ws + o_agg);
    feats_k<<<75, 256, 0, stream>>>(encoded, ws + o_agg, ws + o_feats);
    mm_naive_bt_k<2><<<75, 256, 0, stream>>>(
        ws + o_feats, 600, 32, 600, fc1_W, 600, fc1_b, ws + o_z);
    mm_naive_bt_k<3><<<(32*1845 + 255)/256, 256, 0, stream>>>(
        ws + o_z, 600, 32, 600, fc2_W, 1845, fc2_b, outf);
}

// Round 3
// 5299.016 us; speedup vs baseline: 3.3510x; 3.3510x over previous
//
#include <hip/hip_runtime.h>
#include <hip/hip_bf16.h>
#include <math.h>

// Problem constants (fixed by setup_inputs)
#define Bb   32
#define Ll   30
#define Hh   300
#define Pp   8
#define Nn   16384
#define Ee   131072
#define NPG  512     // nodes per graph (node_indices = n/512)
#define NI   5       // N_INSTR

typedef __attribute__((ext_vector_type(4))) float f32x4;
typedef __attribute__((ext_vector_type(8))) short s16x8;

__device__ __forceinline__ float eluf(float x){ return x > 0.f ? x : expm1f(x); }
__device__ __forceinline__ float sigf(float x){ return 1.f/(1.f+expf(-x)); }
__device__ __forceinline__ float wave_sum(float s){
    s += __shfl_xor(s, 32); s += __shfl_xor(s, 16); s += __shfl_xor(s, 8);
    s += __shfl_xor(s, 4);  s += __shfl_xor(s, 2);  s += __shfl_xor(s, 1);
    return s;
}
__device__ __forceinline__ unsigned short f2bf(float x){
    unsigned u = __float_as_uint(x);
    unsigned r = u + 0x7FFFu + ((u >> 16) & 1u);
    return (unsigned short)(r >> 16);
}

// ---------------------------------------------------------------------------
// MFMA scored-GEMM: out[m] = sum_c elu( sum_k A[m,k]*S[rowb[m],k] * B[k,c] ) * w[c]
// A: f32 row-major (lda). B: pre-converted bf16, TRANSPOSED [304][bpitch] ([col][k]),
// zero-padded (col>=N -> 0, k>=K -> 0). wpad: [304] f32 zero-padded.
// Block: 256 thr = 4 waves (2x2): wr in {0,1} x 32 rows, wc in {0,1} x ~160 cols.
// 64 rows per block. BK=32 (one mfma_16x16x32 K-step).
// ---------------------------------------------------------------------------
__global__ __launch_bounds__(256, 2) void mfma_score_k(
    const float* __restrict__ A, int lda, int K,
    const unsigned short* __restrict__ Bt, int bpitch,
    const float* __restrict__ S, int sstride, const int* __restrict__ rowb,
    const float* __restrict__ wpad,
    float* __restrict__ out)
{
    __shared__ unsigned short As[64 * 40];   // row pitch 40 bf16 (80 B) -> <=2-way bank conflict
    __shared__ float red[2][2][32];

    const int t = threadIdx.x;
    const int wave = t >> 6, lane = t & 63;
    const int wr = wave >> 1, wc = wave & 1;
    const int rowBlock = blockIdx.x * 64;

    const int sr = t >> 2;            // staging row 0..63
    const int sk = (t & 3) * 8;       // staging k sub-offset {0,8,16,24}
    const int grow = rowBlock + sr;
    const int bb = rowb[grow];
    const float* arow = A + (size_t)grow * lda;
    const float* srow = S + (size_t)bb * sstride;

    f32x4 acc[2][10];
    #pragma unroll
    for (int rt = 0; rt < 2; rt++)
        #pragma unroll
        for (int ct = 0; ct < 10; ct++) acc[rt][ct] = (f32x4){0.f,0.f,0.f,0.f};

    const int nsteps = (K + 31) >> 5;

    float a8[8], s8[8];
    // prefetch k-step 0
    {
        int k = sk;
        if (k + 8 <= K) {
            float4 v0 = *(const float4*)(arow + k), v1 = *(const float4*)(arow + k + 4);
            a8[0]=v0.x; a8[1]=v0.y; a8[2]=v0.z; a8[3]=v0.w; a8[4]=v1.x; a8[5]=v1.y; a8[6]=v1.z; a8[7]=v1.w;
            float4 w0 = *(const float4*)(srow + k), w1 = *(const float4*)(srow + k + 4);
            s8[0]=w0.x; s8[1]=w0.y; s8[2]=w0.z; s8[3]=w0.w; s8[4]=w1.x; s8[5]=w1.y; s8[6]=w1.z; s8[7]=w1.w;
        } else {
            #pragma unroll
            for (int j = 0; j < 8; j++){ int kk = k + j; a8[j] = (kk < K) ? arow[kk] : 0.f; s8[j] = (kk < K) ? srow[kk] : 0.f; }
        }
    }

    for (int kt = 0; kt < nsteps; ++kt) {
        // ---- pack A*S -> bf16 LDS ----
        {
            s16x8 v;
            #pragma unroll
            for (int j = 0; j < 8; j++) v[j] = (short)f2bf(a8[j] * s8[j]);
            *(s16x8*)&As[sr * 40 + sk] = v;
        }
        __syncthreads();
        // ---- prefetch next k-step (hides under MFMA) ----
        if (kt + 1 < nsteps) {
            int k = ((kt + 1) << 5) + sk;
            if (k + 8 <= K) {
                float4 v0 = *(const float4*)(arow + k), v1 = *(const float4*)(arow + k + 4);
                a8[0]=v0.x; a8[1]=v0.y; a8[2]=v0.z; a8[3]=v0.w; a8[4]=v1.x; a8[5]=v1.y; a8[6]=v1.z; a8[7]=v1.w;
                float4 w0 = *(const float4*)(srow + k), w1 = *(const float4*)(srow + k + 4);
                s8[0]=w0.x; s8[1]=w0.y; s8[2]=w0.z; s8[3]=w0.w; s8[4]=w1.x; s8[5]=w1.y; s8[6]=w1.z; s8[7]=w1.w;
            } else {
                #pragma unroll
                for (int j = 0; j < 8; j++){ int kk = k + j; a8[j] = (kk < K) ? arow[kk] : 0.f; s8[j] = (kk < K) ? srow[kk] : 0.f; }
            }
        }
        // ---- fragments + MFMA ----
        const int k0 = kt << 5;
        s16x8 af0 = *(s16x8*)&As[(wr * 32 + (lane & 15)) * 40 + (lane >> 4) * 8];
        s16x8 af1 = *(s16x8*)&As[(wr * 32 + 16 + (lane & 15)) * 40 + (lane >> 4) * 8];
        #pragma unroll
        for (int ct = 0; ct < 10; ct++) {
            if (wc == 1 && ct == 9) continue;          // cols 304+ don't exist
            int col = wc * 160 + ct * 16 + (lane & 15);
            s16x8 bf = *(const s16x8*)&Bt[(size_t)col * bpitch + k0 + (lane >> 4) * 8];
            acc[0][ct] = __builtin_amdgcn_mfma_f32_16x16x32_bf16(af0, bf, acc[0][ct], 0, 0, 0);
            acc[1][ct] = __builtin_amdgcn_mfma_f32_16x16x32_bf16(af1, bf, acc[1][ct], 0, 0, 0);
        }
        __syncthreads();
    }

    // ---- epilogue: per-row sum of elu(C)*w ----
    // C mapping (16x16x32): col = lane&15, row = (lane>>4)*4 + i
    float p[2][4];
    #pragma unroll
    for (int rt = 0; rt < 2; rt++)
        #pragma unroll
        for (int i = 0; i < 4; i++) p[rt][i] = 0.f;
    #pragma unroll
    for (int ct = 0; ct < 10; ct++) {
        if (wc == 1 && ct == 9) continue;
        int col = wc * 160 + ct * 16 + (lane & 15);
        float wv = wpad[col];
        #pragma unroll
        for (int rt = 0; rt < 2; rt++)
            #pragma unroll
            for (int i = 0; i < 4; i++)
                p[rt][i] += eluf(acc[rt][ct][i]) * wv;
    }
    // reduce over the 16 lanes of each quarter (cols)
    #pragma unroll
    for (int m = 1; m <= 8; m <<= 1) {
        #pragma unroll
        for (int rt = 0; rt < 2; rt++)
            #pragma unroll
            for (int i = 0; i < 4; i++)
                p[rt][i] += __shfl_xor(p[rt][i], m);
    }
    if ((lane & 15) == 0) {
        int q = lane >> 4;
        #pragma unroll
        for (int rt = 0; rt < 2; rt++)
            #pragma unroll
            for (int i = 0; i < 4; i++)
                red[wr][wc][rt * 16 + q * 4 + i] = p[rt][i];
    }
    __syncthreads();
    if (t < 64) {
        int wrr = t >> 5, r = t & 31;
        out[rowBlock + wrr * 32 + r] = red[wrr][0][r] + red[wrr][1][r];
    }
}

// Build transposed zero-padded bf16 B: Bt[col][k], col<304, k<bpitch
__global__ void build_bt_k(const float* __restrict__ B, int K, int N, int bpitch,
                           unsigned short* __restrict__ Bt)
{
    int idx = blockIdx.x * 256 + threadIdx.x;
    if (idx >= 304 * bpitch) return;
    int col = idx / bpitch, k = idx - col * bpitch;
    float v = (col < N && k < K) ? B[(size_t)k * N + col] : 0.f;
    Bt[idx] = f2bf(v);
}

__global__ void wpad_k(const float* __restrict__ wn, const float* __restrict__ wr,
                       float* __restrict__ wnp, float* __restrict__ wrp)
{
    int i = threadIdx.x;
    if (i < 304) { wnp[i] = (i < 300) ? wn[i] : 0.f; wrp[i] = (i < 300) ? wr[i] : 0.f; }
}

// ---------------------------------------------------------------------------
// Tiled f32 GEMM (kept for the small/medium GEMMs)
// ---------------------------------------------------------------------------
template<bool BT, bool ASCALE, int EPI>
__global__ __launch_bounds__(128) void gemm_k(
    const float* __restrict__ A, int lda, int M, int K,
    const float* __restrict__ Bm, int N,
    const float* __restrict__ S, int sstride, const int* __restrict__ rowb,
    const float* __restrict__ w,
    float* __restrict__ Cf)
{
    __shared__ __align__(16) float As[16*36];
    __shared__ __align__(16) float Bs[16*324];

    const int t  = threadIdx.x;
    const int tr = t & 7;
    const int tc = t >> 3;
    const int rowBlock = blockIdx.x * 32;
    const int colBase  = blockIdx.y * 320;

    float acc[4][20];
    #pragma unroll
    for (int r = 0; r < 4; r++){
        #pragma unroll
        for (int c = 0; c < 20; c++) acc[r][c] = 0.f;
    }

    const int ar = rowBlock + (t >> 2);
    const int kc = (t & 3) * 4;

    const int numT = (K + 15) >> 4;
    for (int kt = 0; kt < numT; ++kt) {
        const int k0 = kt << 4;
        #pragma unroll
        for (int j = 0; j < 4; j++){
            int kk = k0 + kc + j;
            float x = 0.f;
            if (ar < M && kk < K) x = A[(size_t)ar * lda + kk];
            As[(kc + j) * 36 + (t >> 2)] = x;
        }
        if (!BT) {
            #pragma unroll
            for (int i = 0; i < 40; i++){
                int idx = i * 128 + t;
                int k = idx / 320;
                int c = idx - k * 320;
                int gk = k0 + k, gc = colBase + c;
                float v = 0.f;
                if (gk < K && gc < N) v = Bm[(size_t)gk * N + gc];
                Bs[k * 324 + c] = v;
            }
        } else {
            #pragma unroll
            for (int i = 0; i < 40; i++){
                int idx = i * 128 + t;
                int k = idx & 15;
                int c = idx >> 4;
                int gk = k0 + k, gc = colBase + c;
                float v = 0.f;
                if (gk < K && gc < N) v = Bm[(size_t)gc * K + gk];
                Bs[k * 324 + c] = v;
            }
        }
        __syncthreads();
        #pragma unroll
        for (int kk = 0; kk < 16; ++kk){
            float4 a4 = *(const float4*)&As[kk * 36 + tr * 4];
            float av[4] = {a4.x, a4.y, a4.z, a4.w};
            float bv[20];
            #pragma unroll
            for (int j = 0; j < 5; j++){
                float4 b4 = *(const float4*)&Bs[kk * 324 + tc * 20 + j * 4];
                bv[j*4+0] = b4.x; bv[j*4+1] = b4.y; bv[j*4+2] = b4.z; bv[j*4+3] = b4.w;
            }
            #pragma unroll
            for (int r = 0; r < 4; r++){
                #pragma unroll
                for (int c = 0; c < 20; c++)
                    acc[r][c] = fmaf(av[r], bv[c], acc[r][c]);
            }
        }
        __syncthreads();
    }

    #pragma unroll
    for (int r = 0; r < 4; r++){
        int row = rowBlock + tr * 4 + r;
        if (row >= M) continue;
        #pragma unroll
        for (int c = 0; c < 20; c++){
            int col = colBase + tc * 20 + c;
            if (col >= N) continue;
            Cf[(size_t)row * N + col] = acc[r][c];
        }
    }
}

// Naive thread-per-output A @ B^T for tiny-M GEMMs (M=32).
template<int EPI>
__global__ void mm_naive_bt_k(const float* __restrict__ A, int lda, int M, int K,
                              const float* __restrict__ Bm, int N,
                              const float* __restrict__ bias,
                              float* __restrict__ Cf)
{
    int idx = blockIdx.x * 256 + threadIdx.x;
    if (idx >= M * N) return;
    int m = idx / N;
    int j = idx - m * N;
    const float* arow = A + (size_t)m * lda;
    const float* brow = Bm + (size_t)j * K;
    float s = 0.f;
    for (int k = 0; k < K; k++) s += arow[k] * brow[k];
    if (EPI == 0) Cf[idx] = s;
    else if (EPI == 2) Cf[idx] = eluf(s + bias[j]);
    else Cf[idx] = s + bias[j];
}

// ---------------------------------------------------------------------------
__global__ void vocab_build_k(const float* __restrict__ cv, const float* __restrict__ td,
                              float* __restrict__ ve)
{
    int idx = blockIdx.x * 256 + threadIdx.x;
    if (idx < 2001 * 300) ve[idx] = (idx < 2000 * 300) ? cv[idx] : td[idx - 2000 * 300];
}

__global__ void softmax_rows_k(float* __restrict__ X, int nc)
{
    int row = blockIdx.x, t = threadIdx.x;
    __shared__ float red[256];
    size_t base = (size_t)row * nc;
    float m = -3.4e38f;
    for (int i = t; i < nc; i += 256) m = fmaxf(m, X[base + i]);
    red[t] = m; __syncthreads();
    for (int s = 128; s > 0; s >>= 1){ if (t < s) red[t] = fmaxf(red[t], red[t+s]); __syncthreads(); }
    float mx = red[0]; __syncthreads();
    float sm = 0.f;
    for (int i = t; i < nc; i += 256){ float e = expf(X[base + i] - mx); X[base + i] = e; sm += e; }
    red[t] = sm; __syncthreads();
    for (int s = 128; s > 0; s >>= 1){ if (t < s) red[t] += red[t+s]; __syncthreads(); }
    float inv = 1.f / red[0];
    for (int i = t; i < nc; i += 256) X[base + i] *= inv;
}

__global__ void tagged_add_k(const float* __restrict__ sim, const float* __restrict__ q,
                             float* __restrict__ tg)
{
    int idx = blockIdx.x * 256 + threadIdx.x;
    if (idx >= 960 * 300) return;
    int row = idx / 300;
    tg[idx] += sim[(size_t)row * 2001 + 2000] * q[idx];
}

__global__ __launch_bounds__(256) void lstm_step_k(
    const float* __restrict__ xW, const float* __restrict__ Whh,
    const float* __restrict__ bih, const float* __restrict__ bhh,
    const float* __restrict__ h_in, const float* __restrict__ c_in,
    float* __restrict__ h_out, float* __restrict__ c_out,
    const int* __restrict__ lengths, int t)
{
    int wid = blockIdx.x * 4 + (threadIdx.x >> 6);
    int lane = threadIdx.x & 63;
    int b = wid / Hh, hid = wid - b * Hh;
    float hv[5];
    #pragma unroll
    for (int p = 0; p < 5; p++){ int k = lane + p * 64; hv[p] = (k < Hh) ? h_in[b * Hh + k] : 0.f; }
    float d[4];
    #pragma unroll
    for (int g = 0; g < 4; g++){
        const float* wr = Whh + (size_t)(g * Hh + hid) * Hh;
        float s = 0.f;
        #pragma unroll
        for (int p = 0; p < 5; p++){ int k = lane + p * 64; if (k < Hh) s += hv[p] * wr[k]; }
        d[g] = wave_sum(s);
    }
    if (lane == 0){
        const float* xr = xW + (size_t)(b * Ll + t) * 1200;
        float i_ = sigf (xr[hid]       + bih[hid]       + bhh[hid]       + d[0]);
        float f_ = sigf (xr[300 + hid] + bih[300 + hid] + bhh[300 + hid] + d[1]);
        float g_ = tanhf(xr[600 + hid] + bih[600 + hid] + bhh[600 + hid] + d[2]);
        float o_ = sigf (xr[900 + hid] + bih[900 + hid] + bhh[900 + hid] + d[3]);
        float cn = f_ * c_in[b * Hh + hid] + i_ * g_;
        float hn = o_ * tanhf(cn);
        bool msk = t < lengths[b];
        h_out[b * Hh + hid] = msk ? hn : h_in[b * Hh + hid];
        c_out[b * Hh + hid] = msk ? cn : c_in[b * Hh + hid];
    }
}

__global__ __launch_bounds__(256) void rnn_iter_k(
    const float* __restrict__ exG, const float* __restrict__ Whh,
    const float* __restrict__ bih, const float* __restrict__ bhh,
    const float* __restrict__ hx_in, float* __restrict__ hx_out,
    float* __restrict__ hidden, int it)
{
    int wid = blockIdx.x * 4 + (threadIdx.x >> 6);
    int lane = threadIdx.x & 63;
    int b = wid / Hh, hid = wid - b * Hh;
    const float* wr = Whh + (size_t)hid * Hh;
    float s = 0.f;
    #pragma unroll
    for (int p = 0; p < 5; p++){ int k = lane + p * 64; if (k < Hh) s += hx_in[b * Hh + k] * wr[k]; }
    s = wave_sum(s);
    if (lane == 0){
        float v = exG[b * Hh + hid] + bih[hid] + bhh[hid] + s;
        v = fmaxf(v, 0.f);
        hx_out[b * Hh + hid] = v;
        hidden[((size_t)b * NI + it) * Hh + hid] = v;
    }
}

__global__ __launch_bounds__(256) void scores_instr_k(
    const float* __restrict__ hidden, const float* __restrict__ tagged,
    const int* __restrict__ lengths, float* __restrict__ instr)
{
    __shared__ float sc[4][32];
    int wv = threadIdx.x >> 6;
    int wid = blockIdx.x * 4 + wv;
    int lane = threadIdx.x & 63;
    int b = wid / NI;
    const float* hr = hidden + (size_t)wid * Hh;
    float hv[5];
    #pragma unroll
    for (int p = 0; p < 5; p++){ int k = lane + p * 64; hv[p] = (k < Hh) ? hr[k] : 0.f; }
    int len = lengths[b];
    for (int l = 0; l < Ll; l++){
        const float* trw = tagged + ((size_t)b * Ll + l) * Hh;
        float s = 0.f;
        #pragma unroll
        for (int p = 0; p < 5; p++){ int k = lane + p * 64; if (k < Hh) s += hv[p] * trw[k]; }
        s = wave_sum(s);
        if (lane == 0) sc[wv][l] = s;
    }
    __syncthreads();
    float mx = -3.4e38f;
    for (int l = 0; l < len; l++) mx = fmaxf(mx, sc[wv][l]);
    float sum = 0.f;
    for (int l = 0; l < len; l++) sum += expf(sc[wv][l] - mx);
    float inv = 1.f / sum;
    float a[5] = {0.f,0.f,0.f,0.f,0.f};
    for (int l = 0; l < len; l++){
        float pl = expf(sc[wv][l] - mx) * inv;
        const float* trw = tagged + ((size_t)b * Ll + l) * Hh;
        #pragma unroll
        for (int p = 0; p < 5; p++){ int k = lane + p * 64; if (k < Hh) a[p] += pl * trw[k]; }
    }
    #pragma unroll
    for (int p = 0; p < 5; p++){ int k = lane + p * 64; if (k < Hh) instr[(size_t)wid * Hh + k] = a[p]; }
}

__global__ __launch_bounds__(256) void prop_softmax_k(
    const float* __restrict__ instr, int ii, const float* __restrict__ pemb,
    float* __restrict__ psim, float* __restrict__ rsim)
{
    int wid = blockIdx.x * 4 + (threadIdx.x >> 6);
    int lane = threadIdx.x & 63;
    const float* ir = instr + ((size_t)wid * NI + ii) * Hh;
    float iv[5];
    #pragma unroll
    for (int p = 0; p < 5; p++){ int k = lane + p * 64; iv[p] = (k < Hh) ? ir[k] : 0.f; }
    float e[9];
    #pragma unroll
    for (int j = 0; j < 9; j++){
        const float* pr = pemb + j * Hh;
        float s = 0.f;
        #pragma unroll
        for (int p = 0; p < 5; p++){ int k = lane + p * 64; if (k < Hh) s += iv[p] * pr[k]; }
        e[j] = wave_sum(s);
    }
    if (lane == 0){
        float mx = e[0];
        #pragma unroll
        for (int j = 1; j < 9; j++) mx = fmaxf(mx, e[j]);
        float sum = 0.f;
        #pragma unroll
        for (int j = 0; j < 9; j++){ e[j] = expf(e[j] - mx); sum += e[j]; }
        float inv = 1.f / sum;
        #pragma unroll
        for (int p = 0; p < 8; p++) psim[wid * 8 + p] = e[p] * inv;
        rsim[wid] = e[8] * inv;
    }
}

__global__ void iscale_k(const float* __restrict__ instr, int step,
                         const float* __restrict__ psim, float* __restrict__ iscale)
{
    int idx = blockIdx.x * 256 + threadIdx.x;
    if (idx >= Bb * 2400) return;
    int b = idx / 2400; int k = idx - b * 2400;
    int p = k / 300;    int h = k - p * 300;
    iscale[idx] = instr[((size_t)b * NI + step) * Hh + h] * psim[b * 8 + p];
}

__global__ void count_k(const int* __restrict__ ni, int* __restrict__ cnt)
{
    int n = blockIdx.x * 256 + threadIdx.x;
    if (n < Nn) atomicAdd(&cnt[ni[n]], 1);
}
__global__ void dist_init_k(const int* __restrict__ ni, const int* __restrict__ cnt,
                            float* __restrict__ dist)
{
    int n = blockIdx.x * 256 + threadIdx.x;
    if (n < Nn) dist[n] = 1.f / (float)cnt[ni[n]];
}

__global__ void edge_msg_k(const int* __restrict__ ei, const float* __restrict__ es,
                           const float* __restrict__ dist, float* __restrict__ msgdot)
{
    int e = blockIdx.x * 256 + threadIdx.x;
    if (e < Ee){
        int s = ei[e];
        int d = ei[Ee + e];
        atomicAdd(&msgdot[d], dist[s] * es[e]);
    }
}

__global__ __launch_bounds__(256) void seg_update_k(
    const float* __restrict__ nscore, const float* __restrict__ msgdot,
    const float* __restrict__ rsim, float* __restrict__ dist)
{
    int b = blockIdx.x, t = threadIdx.x;
    __shared__ float red[256];
    int n0 = b * NPG;
    float a1 = nscore[n0 + t], a2 = nscore[n0 + 256 + t];
    float m1 = msgdot[n0 + t], m2 = msgdot[n0 + 256 + t];

    red[t] = fmaxf(a1, a2); __syncthreads();
    for (int s = 128; s > 0; s >>= 1){ if (t < s) red[t] = fmaxf(red[t], red[t+s]); __syncthreads(); }
    float mN = red[0]; __syncthreads();
    float e1 = expf(a1 - mN), e2 = expf(a2 - mN);
    red[t] = e1 + e2; __syncthreads();
    for (int s = 128; s > 0; s >>= 1){ if (t < s) red[t] += red[t+s]; __syncthreads(); }
    float sN = red[0]; __syncthreads();

    red[t] = fmaxf(m1, m2); __syncthreads();
    for (int s = 128; s > 0; s >>= 1){ if (t < s) red[t] = fmaxf(red[t], red[t+s]); __syncthreads(); }
    float mM = red[0]; __syncthreads();
    float f1 = expf(m1 - mM), f2 = expf(m2 - mM);
    red[t] = f1 + f2; __syncthreads();
    for (int s = 128; s > 0; s >>= 1){ if (t < s) red[t] += red[t+s]; __syncthreads(); }
    float sM = red[0];

    float rs = rsim[b];
    dist[n0 + t]       = rs * (f1 / sM) + (1.f - rs) * (e1 / sN);
    dist[n0 + 256 + t] = rs * (f2 / sM) + (1.f - rs) * (e2 / sN);
}

__global__ __launch_bounds__(320) void final_agg_k(
    const float* __restrict__ psim, const float* __restrict__ dist,
    const float* __restrict__ na, float* __restrict__ agg)
{
    int chunk = blockIdx.x;
    int b = blockIdx.y;
    int h = threadIdx.x;
    if (h >= Hh) return;
    float ps[8];
    #pragma unroll
    for (int p = 0; p < 8; p++) ps[p] = psim[b * 8 + p];
    float acc = 0.f;
    for (int i = 0; i < 32; i++){
        int n = b * NPG + chunk * 32 + i;
        const float* row = na + (size_t)n * Pp * Hh;
        float wsum = 0.f;
        #pragma unroll
        for (int p = 0; p < 8; p++) wsum += ps[p] * row[p * Hh + h];
        acc += dist[n] * wsum;
    }
    atomicAdd(&agg[b * Hh + h], acc);
}

__global__ void feats_k(const float* __restrict__ enc, const float* __restrict__ agg,
                        float* __restrict__ feats)
{
    int idx = blockIdx.x * 256 + threadIdx.x;
    if (idx >= Bb * 600) return;
    int b = idx / 600, j = idx - b * 600;
    feats[idx] = (j < 300) ? enc[b * 300 + j] : agg[b * 300 + (j - 300)];
}

// ---------------------------------------------------------------------------
extern "C" void kernel_launch(void* const* d_in, const int* in_sizes, int n_in,
                              void* d_out, int out_size, void* d_ws, size_t ws_size,
                              hipStream_t stream)
{
    const float* questions      = (const float*)d_in[0];
    const int*   lengths        = (const int*)  d_in[1];
    const int*   node_indices   = (const int*)  d_in[2];
    const int*   edge_indices   = (const int*)  d_in[3];
    const int*   edge_batch     = (const int*)  d_in[4];
    const float* node_attrs     = (const float*)d_in[5];
    const float* edge_attrs     = (const float*)d_in[6];
    const float* concept_vocab  = (const float*)d_in[7];
    const float* prop_emb       = (const float*)d_in[8];
    const float* tagger_default = (const float*)d_in[9];
    const float* tagger_weight  = (const float*)d_in[10];
    const float* lstm_Wih       = (const float*)d_in[11];
    const float* lstm_Whh       = (const float*)d_in[12];
    const float* lstm_bih       = (const float*)d_in[13];
    const float* lstm_bhh       = (const float*)d_in[14];
    const float* rnn_Wih        = (const float*)d_in[15];
    const float* rnn_Whh        = (const float*)d_in[16];
    const float* rnn_bih        = (const float*)d_in[17];
    const float* rnn_bhh        = (const float*)d_in[18];
    const float* Wnp            = (const float*)d_in[19];
    const float* Wedge          = (const float*)d_in[20];
    const float* w_nscore       = (const float*)d_in[21];
    const float* w_rscore       = (const float*)d_in[22];
    const float* fc1_W          = (const float*)d_in[23];
    const float* fc1_b          = (const float*)d_in[24];
    const float* fc2_W          = (const float*)d_in[25];
    const float* fc2_b          = (const float*)d_in[26];
    float* outf = (float*)d_out;

    float* ws = (float*)d_ws;
    size_t off = 0;
    auto alloc = [&](size_t n){ size_t r = off; off += (n + 63) & ~(size_t)63; return r; };
    size_t o_vocab  = alloc(2001 * 300);
    size_t o_q2     = alloc(960 * 300);
    size_t o_sim    = alloc((size_t)960 * 2001);
    size_t o_tagged = alloc(960 * 300);
    size_t o_xw     = alloc((size_t)960 * 1200);
    size_t o_h0     = alloc(9600);
    size_t o_c0     = alloc(9600);
    size_t o_h1     = alloc(9600);
    size_t o_c1     = alloc(9600);
    size_t o_exg    = alloc(9600);
    size_t o_hx0    = alloc(9600);
    size_t o_hx1    = alloc(9600);
    size_t o_hidden = alloc(48000);
    size_t o_instr  = alloc(48000);
    size_t o_psim   = alloc(256);
    size_t o_rsim   = alloc(64);
    size_t o_iscale = alloc((size_t)Bb * 2400);
    size_t o_nscore = alloc(Nn);
    size_t o_es     = alloc(Ee);
    size_t o_msgdot = alloc(Nn);
    size_t o_dist   = alloc(Nn);
    size_t o_cnt    = alloc(64);
    size_t o_agg    = alloc(9600);
    size_t o_feats  = alloc(19200);
    size_t o_z      = alloc(19200);
    // bf16 transposed weights (sizes in floats = bf16_count/2)
    size_t o_btn    = alloc((size_t)304 * 2400 / 2);   // Wnp^T bf16 [304][2400]
    size_t o_bte    = alloc((size_t)304 * 320 / 2);    // Wedge^T bf16 [304][320]
    size_t o_wn     = alloc(304);
    size_t o_wr     = alloc(304);

    unsigned short* btn = (unsigned short*)(ws + o_btn);
    unsigned short* bte = (unsigned short*)(ws + o_bte);

    // ---- one-time conversions ----
    build_bt_k<<<(304*2400 + 255)/256, 256, 0, stream>>>(Wnp, 2400, 300, 2400, btn);
    build_bt_k<<<(304*320 + 255)/256, 256, 0, stream>>>(Wedge, 300, 300, 320, bte);
    wpad_k<<<1, 320, 0, stream>>>(w_nscore, w_rscore, ws + o_wn, ws + o_wr);

    // ---- tagger: vocab_ext, logits, softmax, tagged ----
    vocab_build_k<<<(2001*300 + 255)/256, 256, 0, stream>>>(concept_vocab, tagger_default, ws + o_vocab);
    gemm_k<false,false,0><<<dim3(30,1), 128, 0, stream>>>(
        questions, 300, 960, 300, tagger_weight, 300, nullptr, 0, nullptr, nullptr, ws + o_q2);
    gemm_k<true,false,0><<<dim3(30,7), 128, 0, stream>>>(
        ws + o_q2, 300, 960, 300, ws + o_vocab, 2001, nullptr, 0, nullptr, nullptr, ws + o_sim);
    softmax_rows_k<<<960, 256, 0, stream>>>(ws + o_sim, 2001);
    gemm_k<false,false,0><<<dim3(30,1), 128, 0, stream>>>(
        ws + o_sim, 2001, 960, 2000, concept_vocab, 300, nullptr, 0, nullptr, nullptr, ws + o_tagged);
    tagged_add_k<<<1125, 256, 0, stream>>>(ws + o_sim, questions, ws + o_tagged);

    // ---- LSTM ----
    gemm_k<true,false,0><<<dim3(30,4), 128, 0, stream>>>(
        ws + o_tagged, 300, 960, 300, lstm_Wih, 1200, nullptr, 0, nullptr, nullptr, ws + o_xw);
    hipMemsetAsync(ws + o_h0, 0, 2 * 9600 * sizeof(float), stream);
    float* hbuf[2] = {ws + o_h0, ws + o_h1};
    float* cbuf[2] = {ws + o_c0, ws + o_c1};
    for (int t = 0; t < Ll; t++){
        int a = t & 1, b2 = 1 - a;
        lstm_step_k<<<2400, 256, 0, stream>>>(ws + o_xw, lstm_Whh, lstm_bih, lstm_bhh,
            hbuf[a], cbuf[a], hbuf[b2], cbuf[b2], lengths, t);
    }
    const float* encoded = ws + o_h0;

    // ---- RNN instruction decoder ----
    mm_naive_bt_k<0><<<(9600 + 255)/256, 256, 0, stream>>>(
        encoded, 300, 32, 300, rnn_Wih, 300, nullptr, ws + o_exg);
    hipMemsetAsync(ws + o_hx0, 0, 9600 * sizeof(float), stream);
    float* hxb[2] = {ws + o_hx0, ws + o_hx1};
    for (int it = 0; it < NI; it++){
        int a = it & 1;
        rnn_iter_k<<<2400, 256, 0, stream>>>(ws + o_exg, rnn_Whh, rnn_bih, rnn_bhh,
            hxb[a], hxb[1 - a], ws + o_hidden, it);
    }
    scores_instr_k<<<40, 256, 0, stream>>>(ws + o_hidden, ws + o_tagged, lengths, ws + o_instr);

    // ---- distribution init ----
    hipMemsetAsync(ws + o_cnt, 0, 32 * sizeof(int), stream);
    count_k<<<64, 256, 0, stream>>>(node_indices, (int*)(ws + o_cnt));
    dist_init_k<<<64, 256, 0, stream>>>(node_indices, (int*)(ws + o_cnt), ws + o_dist);

    // ---- 4 message-passing steps ----
    for (int step = 0; step < 4; step++){
        prop_softmax_k<<<8, 256, 0, stream>>>(ws + o_instr, step, prop_emb, ws + o_psim, ws + o_rsim);
        iscale_k<<<300, 256, 0, stream>>>(ws + o_instr, step, ws + o_psim, ws + o_iscale);
        // node scores: (16384 x 2400) @ Wnp_flat(2400 x 300) via bf16 MFMA, fused elu-dot epilogue
        mfma_score_k<<<Nn/64, 256, 0, stream>>>(
            node_attrs, 2400, 2400, btn, 2400,
            ws + o_iscale, 2400, node_indices, ws + o_wn, ws + o_nscore);
        // edge scores: (131072 x 300) @ Wedge(300 x 300) via bf16 MFMA
        mfma_score_k<<<Ee/64, 256, 0, stream>>>(
            edge_attrs, 300, 300, bte, 320,
            ws + o_instr + step * 300, NI * 300, edge_batch, ws + o_wr, ws + o_es);
        hipMemsetAsync(ws + o_msgdot, 0, Nn * sizeof(float), stream);
        edge_msg_k<<<512, 256, 0, stream>>>(edge_indices, ws + o_es, ws + o_dist, ws + o_msgdot);
        seg_update_k<<<32, 256, 0, stream>>>(ws + o_nscore, ws + o_msgdot, ws + o_rsim, ws + o_dist);
    }

    // ---- final aggregation + FCs ----
    prop_softmax_k<<<8, 256, 0, stream>>>(ws + o_instr, 4, prop_emb, ws + o_psim, ws + o_rsim);
    hipMemsetAsync(ws + o_agg, 0, 9600 * sizeof(float), stream);
    final_agg_k<<<dim3(16,32), 320, 0, stream>>>(ws + o_psim, ws + o_dist, node_attrs, ws + o_agg);
    feats_k<<<75, 256, 0, stream>>>(encoded, ws + o_agg, ws + o_feats);
    mm_naive_bt_k<2><<<75, 256, 0, stream>>>(
        ws + o_feats, 600, 32, 600, fc1_W, 600, fc1_b, ws + o_z);
    mm_naive_bt_k<3><<<(32*1845 + 255)/256, 256, 0, stream>>>(
        ws + o_z, 600, 32, 600, fc2_W, 1845, fc2_b, outf);
}

// Round 4
// 3315.652 us; speedup vs baseline: 5.3555x; 1.5982x over previous
//
#include <hip/hip_runtime.h>
#include <hip/hip_bf16.h>
#include <math.h>

// Problem constants (fixed by setup_inputs)
#define Bb   32
#define Ll   30
#define Hh   300
#define Pp   8
#define Nn   16384
#define Ee   131072
#define NPG  512     // nodes per graph (node_indices = n/512)
#define NI   5       // N_INSTR

typedef __attribute__((ext_vector_type(4))) float f32x4;
typedef __attribute__((ext_vector_type(8))) short s16x8;

__device__ __forceinline__ float eluf(float x){ return x > 0.f ? x : expm1f(x); }
__device__ __forceinline__ float sigf(float x){ return 1.f/(1.f+expf(-x)); }
__device__ __forceinline__ float wave_sum(float s){
    s += __shfl_xor(s, 32); s += __shfl_xor(s, 16); s += __shfl_xor(s, 8);
    s += __shfl_xor(s, 4);  s += __shfl_xor(s, 2);  s += __shfl_xor(s, 1);
    return s;
}
__device__ __forceinline__ unsigned short f2bf(float x){
    unsigned u = __float_as_uint(x);
    unsigned r = u + 0x7FFFu + ((u >> 16) & 1u);
    return (unsigned short)(r >> 16);
}

// ---------------------------------------------------------------------------
// MFMA scored-GEMM: out[m] = sum_c elu( sum_k A[m,k]*S[rowb[m],k] * B[k,c] ) * w[c]
// ---------------------------------------------------------------------------
__global__ __launch_bounds__(256, 2) void mfma_score_k(
    const float* __restrict__ A, int lda, int K,
    const unsigned short* __restrict__ Bt, int bpitch,
    const float* __restrict__ S, int sstride, const int* __restrict__ rowb,
    const float* __restrict__ wpad,
    float* __restrict__ out)
{
    __shared__ unsigned short As[64 * 40];
    __shared__ float red[2][2][32];

    const int t = threadIdx.x;
    const int wave = t >> 6, lane = t & 63;
    const int wr = wave >> 1, wc = wave & 1;
    const int rowBlock = blockIdx.x * 64;

    const int sr = t >> 2;
    const int sk = (t & 3) * 8;
    const int grow = rowBlock + sr;
    const int bb = rowb[grow];
    const float* arow = A + (size_t)grow * lda;
    const float* srow = S + (size_t)bb * sstride;

    f32x4 acc[2][10];
    #pragma unroll
    for (int rt = 0; rt < 2; rt++)
        #pragma unroll
        for (int ct = 0; ct < 10; ct++) acc[rt][ct] = (f32x4){0.f,0.f,0.f,0.f};

    const int nsteps = (K + 31) >> 5;

    float a8[8], s8[8];
    {
        int k = sk;
        if (k + 8 <= K) {
            float4 v0 = *(const float4*)(arow + k), v1 = *(const float4*)(arow + k + 4);
            a8[0]=v0.x; a8[1]=v0.y; a8[2]=v0.z; a8[3]=v0.w; a8[4]=v1.x; a8[5]=v1.y; a8[6]=v1.z; a8[7]=v1.w;
            float4 w0 = *(const float4*)(srow + k), w1 = *(const float4*)(srow + k + 4);
            s8[0]=w0.x; s8[1]=w0.y; s8[2]=w0.z; s8[3]=w0.w; s8[4]=w1.x; s8[5]=w1.y; s8[6]=w1.z; s8[7]=w1.w;
        } else {
            #pragma unroll
            for (int j = 0; j < 8; j++){ int kk = k + j; a8[j] = (kk < K) ? arow[kk] : 0.f; s8[j] = (kk < K) ? srow[kk] : 0.f; }
        }
    }

    for (int kt = 0; kt < nsteps; ++kt) {
        {
            s16x8 v;
            #pragma unroll
            for (int j = 0; j < 8; j++) v[j] = (short)f2bf(a8[j] * s8[j]);
            *(s16x8*)&As[sr * 40 + sk] = v;
        }
        __syncthreads();
        if (kt + 1 < nsteps) {
            int k = ((kt + 1) << 5) + sk;
            if (k + 8 <= K) {
                float4 v0 = *(const float4*)(arow + k), v1 = *(const float4*)(arow + k + 4);
                a8[0]=v0.x; a8[1]=v0.y; a8[2]=v0.z; a8[3]=v0.w; a8[4]=v1.x; a8[5]=v1.y; a8[6]=v1.z; a8[7]=v1.w;
                float4 w0 = *(const float4*)(srow + k), w1 = *(const float4*)(srow + k + 4);
                s8[0]=w0.x; s8[1]=w0.y; s8[2]=w0.z; s8[3]=w0.w; s8[4]=w1.x; s8[5]=w1.y; s8[6]=w1.z; s8[7]=w1.w;
            } else {
                #pragma unroll
                for (int j = 0; j < 8; j++){ int kk = k + j; a8[j] = (kk < K) ? arow[kk] : 0.f; s8[j] = (kk < K) ? srow[kk] : 0.f; }
            }
        }
        const int k0 = kt << 5;
        s16x8 af0 = *(s16x8*)&As[(wr * 32 + (lane & 15)) * 40 + (lane >> 4) * 8];
        s16x8 af1 = *(s16x8*)&As[(wr * 32 + 16 + (lane & 15)) * 40 + (lane >> 4) * 8];
        #pragma unroll
        for (int ct = 0; ct < 10; ct++) {
            if (wc == 1 && ct == 9) continue;
            int col = wc * 160 + ct * 16 + (lane & 15);
            s16x8 bf = *(const s16x8*)&Bt[(size_t)col * bpitch + k0 + (lane >> 4) * 8];
            acc[0][ct] = __builtin_amdgcn_mfma_f32_16x16x32_bf16(af0, bf, acc[0][ct], 0, 0, 0);
            acc[1][ct] = __builtin_amdgcn_mfma_f32_16x16x32_bf16(af1, bf, acc[1][ct], 0, 0, 0);
        }
        __syncthreads();
    }

    float p[2][4];
    #pragma unroll
    for (int rt = 0; rt < 2; rt++)
        #pragma unroll
        for (int i = 0; i < 4; i++) p[rt][i] = 0.f;
    #pragma unroll
    for (int ct = 0; ct < 10; ct++) {
        if (wc == 1 && ct == 9) continue;
        int col = wc * 160 + ct * 16 + (lane & 15);
        float wv = wpad[col];
        #pragma unroll
        for (int rt = 0; rt < 2; rt++)
            #pragma unroll
            for (int i = 0; i < 4; i++)
                p[rt][i] += eluf(acc[rt][ct][i]) * wv;
    }
    #pragma unroll
    for (int m = 1; m <= 8; m <<= 1) {
        #pragma unroll
        for (int rt = 0; rt < 2; rt++)
            #pragma unroll
            for (int i = 0; i < 4; i++)
                p[rt][i] += __shfl_xor(p[rt][i], m);
    }
    if ((lane & 15) == 0) {
        int q = lane >> 4;
        #pragma unroll
        for (int rt = 0; rt < 2; rt++)
            #pragma unroll
            for (int i = 0; i < 4; i++)
                red[wr][wc][rt * 16 + q * 4 + i] = p[rt][i];
    }
    __syncthreads();
    if (t < 64) {
        int wrr = t >> 5, r = t & 31;
        out[rowBlock + wrr * 32 + r] = red[wrr][0][r] + red[wrr][1][r];
    }
}

__global__ void build_bt_k(const float* __restrict__ B, int K, int N, int bpitch,
                           unsigned short* __restrict__ Bt)
{
    int idx = blockIdx.x * 256 + threadIdx.x;
    if (idx >= 304 * bpitch) return;
    int col = idx / bpitch, k = idx - col * bpitch;
    float v = (col < N && k < K) ? B[(size_t)k * N + col] : 0.f;
    Bt[idx] = f2bf(v);
}

__global__ void wpad_k(const float* __restrict__ wn, const float* __restrict__ wr,
                       float* __restrict__ wnp, float* __restrict__ wrp)
{
    int i = threadIdx.x;
    if (i < 304) { wnp[i] = (i < 300) ? wn[i] : 0.f; wrp[i] = (i < 300) ? wr[i] : 0.f; }
}

// ---------------------------------------------------------------------------
// Parallel f32 GEMM: 64x64 tile, 256 threads, 4x4 per thread, optional split-K.
// BT=false: B is (K,N) ldb=N.  BT=true: B is (N,K) ldb=K.
// EPI 0: store.  EPI 1: atomicAdd (C must be pre-zeroed; use with gridDim.z>1).
// ---------------------------------------------------------------------------
template<bool BT, int EPI>
__global__ __launch_bounds__(256) void gemm2_k(
    const float* __restrict__ A, int lda, int M, int K, int kChunk,
    const float* __restrict__ Bm, int ldb, int N,
    float* __restrict__ C)
{
    __shared__ float As[16][68];
    __shared__ float Bs[16][68];
    const int t = threadIdx.x;
    const int rowBlock = blockIdx.x * 64, colBase = blockIdx.y * 64;
    const int k0 = blockIdx.z * kChunk;
    const int kend = min(K, k0 + kChunk);

    float acc[4][4] = {{0.f}};
    const int am = t >> 2, ak4 = (t & 3) * 4;
    const int tx = t & 15, ty = t >> 4;

    for (int kt = k0; kt < kend; kt += 16) {
        // stage A (64 rows x 16 k)
        {
            int gr = rowBlock + am;
            #pragma unroll
            for (int j = 0; j < 4; j++) {
                int gk = kt + ak4 + j;
                As[ak4 + j][am] = (gr < M && gk < kend) ? A[(size_t)gr * lda + gk] : 0.f;
            }
        }
        // stage B (16 k x 64 cols)
        if (!BT) {
            int bk = t >> 4, bcc = (t & 15) * 4;
            int gk = kt + bk;
            #pragma unroll
            for (int j = 0; j < 4; j++) {
                int gc = colBase + bcc + j;
                Bs[bk][bcc + j] = (gk < kend && gc < N) ? Bm[(size_t)gk * ldb + gc] : 0.f;
            }
        } else {
            int bc = t >> 2, bk4 = (t & 3) * 4;
            int gc = colBase + bc;
            #pragma unroll
            for (int j = 0; j < 4; j++) {
                int gk = kt + bk4 + j;
                Bs[bk4 + j][bc] = (gk < kend && gc < N) ? Bm[(size_t)gc * ldb + gk] : 0.f;
            }
        }
        __syncthreads();
        #pragma unroll
        for (int kk = 0; kk < 16; kk++) {
            float4 a4 = *(float4*)&As[kk][ty * 4];
            float4 b4 = *(float4*)&Bs[kk][tx * 4];
            float av[4] = {a4.x, a4.y, a4.z, a4.w};
            float bv[4] = {b4.x, b4.y, b4.z, b4.w};
            #pragma unroll
            for (int r = 0; r < 4; r++)
                #pragma unroll
                for (int c = 0; c < 4; c++)
                    acc[r][c] = fmaf(av[r], bv[c], acc[r][c]);
        }
        __syncthreads();
    }

    #pragma unroll
    for (int r = 0; r < 4; r++) {
        int row = rowBlock + ty * 4 + r;
        if (row >= M) continue;
        #pragma unroll
        for (int c = 0; c < 4; c++) {
            int col = colBase + tx * 4 + c;
            if (col >= N) continue;
            if (EPI == 0) C[(size_t)row * N + col] = acc[r][c];
            else atomicAdd(&C[(size_t)row * N + col], acc[r][c]);
        }
    }
}

// Naive thread-per-output A @ B^T for tiny-M GEMMs (M=32).
template<int EPI>
__global__ void mm_naive_bt_k(const float* __restrict__ A, int lda, int M, int K,
                              const float* __restrict__ Bm, int N,
                              const float* __restrict__ bias,
                              float* __restrict__ Cf)
{
    int idx = blockIdx.x * 256 + threadIdx.x;
    if (idx >= M * N) return;
    int m = idx / N;
    int j = idx - m * N;
    const float* arow = A + (size_t)m * lda;
    const float* brow = Bm + (size_t)j * K;
    float s = 0.f;
    for (int k = 0; k < K; k++) s += arow[k] * brow[k];
    if (EPI == 0) Cf[idx] = s;
    else if (EPI == 2) Cf[idx] = eluf(s + bias[j]);
    else Cf[idx] = s + bias[j];
}

// dst[C][R] = src[R][C]
__global__ void transpose_k(const float* __restrict__ src, int R, int C,
                            float* __restrict__ dst)
{
    int idx = blockIdx.x * 256 + threadIdx.x;
    if (idx >= R * C) return;
    int r = idx / C, c = idx - r * C;
    dst[(size_t)c * R + r] = src[idx];
}

// ---------------------------------------------------------------------------
__global__ void vocab_build_k(const float* __restrict__ cv, const float* __restrict__ td,
                              float* __restrict__ ve)
{
    int idx = blockIdx.x * 256 + threadIdx.x;
    if (idx < 2001 * 300) ve[idx] = (idx < 2000 * 300) ? cv[idx] : td[idx - 2000 * 300];
}

__global__ void softmax_rows_k(float* __restrict__ X, int nc)
{
    int row = blockIdx.x, t = threadIdx.x;
    __shared__ float red[256];
    size_t base = (size_t)row * nc;
    float m = -3.4e38f;
    for (int i = t; i < nc; i += 256) m = fmaxf(m, X[base + i]);
    red[t] = m; __syncthreads();
    for (int s = 128; s > 0; s >>= 1){ if (t < s) red[t] = fmaxf(red[t], red[t+s]); __syncthreads(); }
    float mx = red[0]; __syncthreads();
    float sm = 0.f;
    for (int i = t; i < nc; i += 256){ float e = expf(X[base + i] - mx); X[base + i] = e; sm += e; }
    red[t] = sm; __syncthreads();
    for (int s = 128; s > 0; s >>= 1){ if (t < s) red[t] += red[t+s]; __syncthreads(); }
    float inv = 1.f / red[0];
    for (int i = t; i < nc; i += 256) X[base + i] *= inv;
}

__global__ void tagged_add_k(const float* __restrict__ sim, const float* __restrict__ q,
                             float* __restrict__ tg)
{
    int idx = blockIdx.x * 256 + threadIdx.x;
    if (idx >= 960 * 300) return;
    int row = idx / 300;
    tg[idx] += sim[(size_t)row * 2001 + 2000] * q[idx];
}

// Persistent LSTM: one block per batch, loops over time steps internally.
// WhhT: [300][1200] (k-major).  xW: [B][L][1200].
__global__ __launch_bounds__(320) void lstm_all_k(
    const float* __restrict__ xW, const float* __restrict__ WhhT,
    const float* __restrict__ bih, const float* __restrict__ bhh,
    const int* __restrict__ lengths, float* __restrict__ encoded)
{
    __shared__ float hs[304];
    const int b = blockIdx.x, i = threadIdx.x;
    const bool act = i < 300;
    float bs0 = 0.f, bs1 = 0.f, bs2 = 0.f, bs3 = 0.f;
    if (act) {
        bs0 = bih[i]       + bhh[i];
        bs1 = bih[300 + i] + bhh[300 + i];
        bs2 = bih[600 + i] + bhh[600 + i];
        bs3 = bih[900 + i] + bhh[900 + i];
        hs[i] = 0.f;
    }
    float h = 0.f, c = 0.f;
    const int len = lengths[b];
    for (int t = 0; t < len; t++) {
        __syncthreads();
        if (act) {
            float d0 = 0.f, d1 = 0.f, d2 = 0.f, d3 = 0.f;
            #pragma unroll 4
            for (int k = 0; k < 300; k++) {
                float hk = hs[k];
                const float* wr = WhhT + (size_t)k * 1200;
                d0 = fmaf(hk, wr[i], d0);
                d1 = fmaf(hk, wr[300 + i], d1);
                d2 = fmaf(hk, wr[600 + i], d2);
                d3 = fmaf(hk, wr[900 + i], d3);
            }
            const float* xr = xW + ((size_t)b * Ll + t) * 1200;
            float i_ = sigf (xr[i]       + bs0 + d0);
            float f_ = sigf (xr[300 + i] + bs1 + d1);
            float g_ = tanhf(xr[600 + i] + bs2 + d2);
            float o_ = sigf (xr[900 + i] + bs3 + d3);
            c = f_ * c + i_ * g_;
            h = o_ * tanhf(c);
        }
        __syncthreads();
        if (act) hs[i] = h;
    }
    if (act) encoded[b * 300 + i] = h;
}

// Persistent RNN decoder: computes exG internally, then 5 relu iterations.
// WihT, WhhT: [300][300] (k-major).
__global__ __launch_bounds__(320) void rnn_all_k(
    const float* __restrict__ enc, const float* __restrict__ WihT,
    const float* __restrict__ WhhT,
    const float* __restrict__ bih, const float* __restrict__ bhh,
    float* __restrict__ hidden)
{
    __shared__ float es[304];
    __shared__ float hs[304];
    const int b = blockIdx.x, i = threadIdx.x;
    const bool act = i < 300;
    if (act) { es[i] = enc[b * 300 + i]; hs[i] = 0.f; }
    __syncthreads();
    float ex = 0.f;
    if (act) {
        #pragma unroll 4
        for (int k = 0; k < 300; k++)
            ex = fmaf(es[k], WihT[(size_t)k * 300 + i], ex);
        ex += bih[i] + bhh[i];
    }
    for (int it = 0; it < NI; it++) {
        __syncthreads();
        float d = 0.f;
        if (act) {
            #pragma unroll 4
            for (int k = 0; k < 300; k++)
                d = fmaf(hs[k], WhhT[(size_t)k * 300 + i], d);
        }
        float v = fmaxf(ex + d, 0.f);
        __syncthreads();
        if (act) { hs[i] = v; hidden[((size_t)b * NI + it) * 300 + i] = v; }
    }
}

__global__ __launch_bounds__(256) void scores_instr_k(
    const float* __restrict__ hidden, const float* __restrict__ tagged,
    const int* __restrict__ lengths, float* __restrict__ instr)
{
    __shared__ float sc[4][32];
    int wv = threadIdx.x >> 6;
    int wid = blockIdx.x * 4 + wv;
    int lane = threadIdx.x & 63;
    int b = wid / NI;
    const float* hr = hidden + (size_t)wid * Hh;
    float hv[5];
    #pragma unroll
    for (int p = 0; p < 5; p++){ int k = lane + p * 64; hv[p] = (k < Hh) ? hr[k] : 0.f; }
    int len = lengths[b];
    for (int l = 0; l < Ll; l++){
        const float* trw = tagged + ((size_t)b * Ll + l) * Hh;
        float s = 0.f;
        #pragma unroll
        for (int p = 0; p < 5; p++){ int k = lane + p * 64; if (k < Hh) s += hv[p] * trw[k]; }
        s = wave_sum(s);
        if (lane == 0) sc[wv][l] = s;
    }
    __syncthreads();
    float mx = -3.4e38f;
    for (int l = 0; l < len; l++) mx = fmaxf(mx, sc[wv][l]);
    float sum = 0.f;
    for (int l = 0; l < len; l++) sum += expf(sc[wv][l] - mx);
    float inv = 1.f / sum;
    float a[5] = {0.f,0.f,0.f,0.f,0.f};
    for (int l = 0; l < len; l++){
        float pl = expf(sc[wv][l] - mx) * inv;
        const float* trw = tagged + ((size_t)b * Ll + l) * Hh;
        #pragma unroll
        for (int p = 0; p < 5; p++){ int k = lane + p * 64; if (k < Hh) a[p] += pl * trw[k]; }
    }
    #pragma unroll
    for (int p = 0; p < 5; p++){ int k = lane + p * 64; if (k < Hh) instr[(size_t)wid * Hh + k] = a[p]; }
}

__global__ __launch_bounds__(256) void prop_softmax_k(
    const float* __restrict__ instr, int ii, const float* __restrict__ pemb,
    float* __restrict__ psim, float* __restrict__ rsim)
{
    int wid = blockIdx.x * 4 + (threadIdx.x >> 6);
    int lane = threadIdx.x & 63;
    const float* ir = instr + ((size_t)wid * NI + ii) * Hh;
    float iv[5];
    #pragma unroll
    for (int p = 0; p < 5; p++){ int k = lane + p * 64; iv[p] = (k < Hh) ? ir[k] : 0.f; }
    float e[9];
    #pragma unroll
    for (int j = 0; j < 9; j++){
        const float* pr = pemb + j * Hh;
        float s = 0.f;
        #pragma unroll
        for (int p = 0; p < 5; p++){ int k = lane + p * 64; if (k < Hh) s += iv[p] * pr[k]; }
        e[j] = wave_sum(s);
    }
    if (lane == 0){
        float mx = e[0];
        #pragma unroll
        for (int j = 1; j < 9; j++) mx = fmaxf(mx, e[j]);
        float sum = 0.f;
        #pragma unroll
        for (int j = 0; j < 9; j++){ e[j] = expf(e[j] - mx); sum += e[j]; }
        float inv = 1.f / sum;
        #pragma unroll
        for (int p = 0; p < 8; p++) psim[wid * 8 + p] = e[p] * inv;
        rsim[wid] = e[8] * inv;
    }
}

__global__ void iscale_k(const float* __restrict__ instr, int step,
                         const float* __restrict__ psim, float* __restrict__ iscale)
{
    int idx = blockIdx.x * 256 + threadIdx.x;
    if (idx >= Bb * 2400) return;
    int b = idx / 2400; int k = idx - b * 2400;
    int p = k / 300;    int h = k - p * 300;
    iscale[idx] = instr[((size_t)b * NI + step) * Hh + h] * psim[b * 8 + p];
}

__global__ void count_k(const int* __restrict__ ni, int* __restrict__ cnt)
{
    int n = blockIdx.x * 256 + threadIdx.x;
    if (n < Nn) atomicAdd(&cnt[ni[n]], 1);
}
__global__ void dist_init_k(const int* __restrict__ ni, const int* __restrict__ cnt,
                            float* __restrict__ dist)
{
    int n = blockIdx.x * 256 + threadIdx.x;
    if (n < Nn) dist[n] = 1.f / (float)cnt[ni[n]];
}

__global__ void edge_msg_k(const int* __restrict__ ei, const float* __restrict__ es,
                           const float* __restrict__ dist, float* __restrict__ msgdot)
{
    int e = blockIdx.x * 256 + threadIdx.x;
    if (e < Ee){
        int s = ei[e];
        int d = ei[Ee + e];
        atomicAdd(&msgdot[d], dist[s] * es[e]);
    }
}

__global__ __launch_bounds__(256) void seg_update_k(
    const float* __restrict__ nscore, const float* __restrict__ msgdot,
    const float* __restrict__ rsim, float* __restrict__ dist)
{
    int b = blockIdx.x, t = threadIdx.x;
    __shared__ float red[256];
    int n0 = b * NPG;
    float a1 = nscore[n0 + t], a2 = nscore[n0 + 256 + t];
    float m1 = msgdot[n0 + t], m2 = msgdot[n0 + 256 + t];

    red[t] = fmaxf(a1, a2); __syncthreads();
    for (int s = 128; s > 0; s >>= 1){ if (t < s) red[t] = fmaxf(red[t], red[t+s]); __syncthreads(); }
    float mN = red[0]; __syncthreads();
    float e1 = expf(a1 - mN), e2 = expf(a2 - mN);
    red[t] = e1 + e2; __syncthreads();
    for (int s = 128; s > 0; s >>= 1){ if (t < s) red[t] += red[t+s]; __syncthreads(); }
    float sN = red[0]; __syncthreads();

    red[t] = fmaxf(m1, m2); __syncthreads();
    for (int s = 128; s > 0; s >>= 1){ if (t < s) red[t] = fmaxf(red[t], red[t+s]); __syncthreads(); }
    float mM = red[0]; __syncthreads();
    float f1 = expf(m1 - mM), f2 = expf(m2 - mM);
    red[t] = f1 + f2; __syncthreads();
    for (int s = 128; s > 0; s >>= 1){ if (t < s) red[t] += red[t+s]; __syncthreads(); }
    float sM = red[0];

    float rs = rsim[b];
    dist[n0 + t]       = rs * (f1 / sM) + (1.f - rs) * (e1 / sN);
    dist[n0 + 256 + t] = rs * (f2 / sM) + (1.f - rs) * (e2 / sN);
}

__global__ __launch_bounds__(320) void final_agg_k(
    const float* __restrict__ psim, const float* __restrict__ dist,
    const float* __restrict__ na, float* __restrict__ agg)
{
    int chunk = blockIdx.x;
    int b = blockIdx.y;
    int h = threadIdx.x;
    if (h >= Hh) return;
    float ps[8];
    #pragma unroll
    for (int p = 0; p < 8; p++) ps[p] = psim[b * 8 + p];
    float acc = 0.f;
    for (int i = 0; i < 32; i++){
        int n = b * NPG + chunk * 32 + i;
        const float* row = na + (size_t)n * Pp * Hh;
        float wsum = 0.f;
        #pragma unroll
        for (int p = 0; p < 8; p++) wsum += ps[p] * row[p * Hh + h];
        acc += dist[n] * wsum;
    }
    atomicAdd(&agg[b * Hh + h], acc);
}

__global__ void feats_k(const float* __restrict__ enc, const float* __restrict__ agg,
                        float* __restrict__ feats)
{
    int idx = blockIdx.x * 256 + threadIdx.x;
    if (idx >= Bb * 600) return;
    int b = idx / 600, j = idx - b * 600;
    feats[idx] = (j < 300) ? enc[b * 300 + j] : agg[b * 300 + (j - 300)];
}

// ---------------------------------------------------------------------------
extern "C" void kernel_launch(void* const* d_in, const int* in_sizes, int n_in,
                              void* d_out, int out_size, void* d_ws, size_t ws_size,
                              hipStream_t stream)
{
    const float* questions      = (const float*)d_in[0];
    const int*   lengths        = (const int*)  d_in[1];
    const int*   node_indices   = (const int*)  d_in[2];
    const int*   edge_indices   = (const int*)  d_in[3];
    const int*   edge_batch     = (const int*)  d_in[4];
    const float* node_attrs     = (const float*)d_in[5];
    const float* edge_attrs     = (const float*)d_in[6];
    const float* concept_vocab  = (const float*)d_in[7];
    const float* prop_emb       = (const float*)d_in[8];
    const float* tagger_default = (const float*)d_in[9];
    const float* tagger_weight  = (const float*)d_in[10];
    const float* lstm_Wih       = (const float*)d_in[11];
    const float* lstm_Whh       = (const float*)d_in[12];
    const float* lstm_bih       = (const float*)d_in[13];
    const float* lstm_bhh       = (const float*)d_in[14];
    const float* rnn_Wih        = (const float*)d_in[15];
    const float* rnn_Whh        = (const float*)d_in[16];
    const float* rnn_bih        = (const float*)d_in[17];
    const float* rnn_bhh        = (const float*)d_in[18];
    const float* Wnp            = (const float*)d_in[19];
    const float* Wedge          = (const float*)d_in[20];
    const float* w_nscore       = (const float*)d_in[21];
    const float* w_rscore       = (const float*)d_in[22];
    const float* fc1_W          = (const float*)d_in[23];
    const float* fc1_b          = (const float*)d_in[24];
    const float* fc2_W          = (const float*)d_in[25];
    const float* fc2_b          = (const float*)d_in[26];
    float* outf = (float*)d_out;

    float* ws = (float*)d_ws;
    size_t off = 0;
    auto alloc = [&](size_t n){ size_t r = off; off += (n + 63) & ~(size_t)63; return r; };
    size_t o_vocab  = alloc(2001 * 300);
    size_t o_q2     = alloc(960 * 300);
    size_t o_sim    = alloc((size_t)960 * 2001);
    size_t o_tagged = alloc(960 * 300);
    size_t o_xw     = alloc((size_t)960 * 1200);
    size_t o_enc    = alloc(9600);
    size_t o_hidden = alloc(48000);
    size_t o_instr  = alloc(48000);
    size_t o_psim   = alloc(256);
    size_t o_rsim   = alloc(64);
    size_t o_iscale = alloc((size_t)Bb * 2400);
    size_t o_nscore = alloc(Nn);
    size_t o_es     = alloc(Ee);
    size_t o_msgdot = alloc(Nn);
    size_t o_dist   = alloc(Nn);
    size_t o_cnt    = alloc(64);
    size_t o_agg    = alloc(9600);
    size_t o_feats  = alloc(19200);
    size_t o_z      = alloc(19200);
    size_t o_btn    = alloc((size_t)304 * 2400 / 2);   // Wnp^T bf16
    size_t o_bte    = alloc((size_t)304 * 320 / 2);    // Wedge^T bf16
    size_t o_wn     = alloc(304);
    size_t o_wr     = alloc(304);
    size_t o_whhT   = alloc(360000);   // lstm Whh^T [300][1200]
    size_t o_rwhhT  = alloc(90000);    // rnn Whh^T [300][300]
    size_t o_rwihT  = alloc(90000);    // rnn Wih^T [300][300]

    unsigned short* btn = (unsigned short*)(ws + o_btn);
    unsigned short* bte = (unsigned short*)(ws + o_bte);

    // ---- one-time conversions (independent) ----
    build_bt_k<<<(304*2400 + 255)/256, 256, 0, stream>>>(Wnp, 2400, 300, 2400, btn);
    build_bt_k<<<(304*320 + 255)/256, 256, 0, stream>>>(Wedge, 300, 300, 320, bte);
    wpad_k<<<1, 320, 0, stream>>>(w_nscore, w_rscore, ws + o_wn, ws + o_wr);
    transpose_k<<<(1200*300 + 255)/256, 256, 0, stream>>>(lstm_Whh, 1200, 300, ws + o_whhT);
    transpose_k<<<(300*300 + 255)/256, 256, 0, stream>>>(rnn_Whh, 300, 300, ws + o_rwhhT);
    transpose_k<<<(300*300 + 255)/256, 256, 0, stream>>>(rnn_Wih, 300, 300, ws + o_rwihT);
    vocab_build_k<<<(2001*300 + 255)/256, 256, 0, stream>>>(concept_vocab, tagger_default, ws + o_vocab);

    // ---- tagger chain ----
    // q2 = questions @ tagger_weight
    gemm2_k<false,0><<<dim3(15,5,1), 256, 0, stream>>>(
        questions, 300, 960, 300, 300, tagger_weight, 300, 300, ws + o_q2);
    // logits = q2 @ vocab_ext^T
    gemm2_k<true,0><<<dim3(15,32,1), 256, 0, stream>>>(
        ws + o_q2, 300, 960, 300, 300, ws + o_vocab, 300, 2001, ws + o_sim);
    softmax_rows_k<<<960, 256, 0, stream>>>(ws + o_sim, 2001);
    // tagged = sim[:, :2000] @ concept_vocab   (split-K 4)
    hipMemsetAsync(ws + o_tagged, 0, 960 * 300 * sizeof(float), stream);
    gemm2_k<false,1><<<dim3(15,5,4), 256, 0, stream>>>(
        ws + o_sim, 2001, 960, 2000, 500, concept_vocab, 300, 300, ws + o_tagged);
    tagged_add_k<<<1125, 256, 0, stream>>>(ws + o_sim, questions, ws + o_tagged);

    // ---- LSTM ----
    // xW = tagged @ lstm_Wih^T
    gemm2_k<true,0><<<dim3(15,19,1), 256, 0, stream>>>(
        ws + o_tagged, 300, 960, 300, 300, lstm_Wih, 300, 1200, ws + o_xw);
    lstm_all_k<<<Bb, 320, 0, stream>>>(ws + o_xw, ws + o_whhT, lstm_bih, lstm_bhh,
                                       lengths, ws + o_enc);

    // ---- RNN instruction decoder + instructions ----
    rnn_all_k<<<Bb, 320, 0, stream>>>(ws + o_enc, ws + o_rwihT, ws + o_rwhhT,
                                      rnn_bih, rnn_bhh, ws + o_hidden);
    scores_instr_k<<<40, 256, 0, stream>>>(ws + o_hidden, ws + o_tagged, lengths, ws + o_instr);

    // ---- distribution init ----
    hipMemsetAsync(ws + o_cnt, 0, 32 * sizeof(int), stream);
    count_k<<<64, 256, 0, stream>>>(node_indices, (int*)(ws + o_cnt));
    dist_init_k<<<64, 256, 0, stream>>>(node_indices, (int*)(ws + o_cnt), ws + o_dist);

    // ---- 4 message-passing steps ----
    for (int step = 0; step < 4; step++){
        prop_softmax_k<<<8, 256, 0, stream>>>(ws + o_instr, step, prop_emb, ws + o_psim, ws + o_rsim);
        iscale_k<<<300, 256, 0, stream>>>(ws + o_instr, step, ws + o_psim, ws + o_iscale);
        mfma_score_k<<<Nn/64, 256, 0, stream>>>(
            node_attrs, 2400, 2400, btn, 2400,
            ws + o_iscale, 2400, node_indices, ws + o_wn, ws + o_nscore);
        mfma_score_k<<<Ee/64, 256, 0, stream>>>(
            edge_attrs, 300, 300, bte, 320,
            ws + o_instr + step * 300, NI * 300, edge_batch, ws + o_wr, ws + o_es);
        hipMemsetAsync(ws + o_msgdot, 0, Nn * sizeof(float), stream);
        edge_msg_k<<<512, 256, 0, stream>>>(edge_indices, ws + o_es, ws + o_dist, ws + o_msgdot);
        seg_update_k<<<32, 256, 0, stream>>>(ws + o_nscore, ws + o_msgdot, ws + o_rsim, ws + o_dist);
    }

    // ---- final aggregation + FCs ----
    prop_softmax_k<<<8, 256, 0, stream>>>(ws + o_instr, 4, prop_emb, ws + o_psim, ws + o_rsim);
    hipMemsetAsync(ws + o_agg, 0, 9600 * sizeof(float), stream);
    final_agg_k<<<dim3(16,32), 320, 0, stream>>>(ws + o_psim, ws + o_dist, node_attrs, ws + o_agg);
    feats_k<<<75, 256, 0, stream>>>(ws + o_enc, ws + o_agg, ws + o_feats);
    mm_naive_bt_k<2><<<75, 256, 0, stream>>>(
        ws + o_feats, 600, 32, 600, fc1_W, 600, fc1_b, ws + o_z);
    mm_naive_bt_k<3><<<(32*1845 + 255)/256, 256, 0, stream>>>(
        ws + o_z, 600, 32, 600, fc2_W, 1845, fc2_b, outf);
}

// Round 5
// 1953.190 us; speedup vs baseline: 9.0913x; 1.6976x over previous
//
#include <hip/hip_runtime.h>
#include <hip/hip_bf16.h>
#include <math.h>

// Problem constants (fixed by setup_inputs)
#define Bb   32
#define Ll   30
#define Hh   300
#define Pp   8
#define Nn   16384
#define Ee   131072
#define NPG  512
#define NI   5

typedef __attribute__((ext_vector_type(4))) float f32x4;
typedef __attribute__((ext_vector_type(8))) short s16x8;

__device__ __forceinline__ float eluf(float x){ return x > 0.f ? x : expm1f(x); }
__device__ __forceinline__ float sigf(float x){ return 1.f/(1.f+expf(-x)); }
__device__ __forceinline__ float wave_sum(float s){
    s += __shfl_xor(s, 32); s += __shfl_xor(s, 16); s += __shfl_xor(s, 8);
    s += __shfl_xor(s, 4);  s += __shfl_xor(s, 2);  s += __shfl_xor(s, 1);
    return s;
}
__device__ __forceinline__ unsigned short f2bf(float x){
    unsigned u = __float_as_uint(x);
    unsigned r = u + 0x7FFFu + ((u >> 16) & 1u);
    return (unsigned short)(r >> 16);
}

// ---------------------------------------------------------------------------
// MFMA scored-GEMM, 2-phase pipelined, A and B both LDS-staged (double-buffered).
// out[m] = sum_c elu( sum_k A[m,k]*S[rowb[m],k] * B[k,c] ) * w[c]
// Bt: bf16 transposed [304][BPITCH] ([col][k]) zero-padded.
// Block: 256 thr = 4 waves (2x2). 64 rows x 304 cols per block. BK=32.
// ---------------------------------------------------------------------------
template<int KK, int BPITCH, int NTILES>
__device__ __forceinline__ void mfma_score_impl(
    const float* __restrict__ A, int lda,
    const unsigned short* __restrict__ Bt,
    const float* __restrict__ S, int sstride, const int* __restrict__ rowb,
    const float* __restrict__ wpad,
    float* __restrict__ out)
{
    __shared__ unsigned short As[2][64*40];    // [buf][row*40 + k]
    __shared__ unsigned short Bs[2][304*36];   // [buf][col*36 + k]
    __shared__ float red[2][2][32];

    const int t = threadIdx.x;
    const int wave = t >> 6, lane = t & 63;
    const int wr = wave >> 1, wc = wave & 1;
    const int rowBlock = blockIdx.x * 64;

    const int sr = t >> 2;            // A staging row 0..63
    const int sk = (t & 3) * 8;       // A staging k sub-offset
    const int grow = rowBlock + sr;
    const int bb = rowb[grow];
    const float* arow = A + (size_t)grow * lda;
    const float* srow = S + (size_t)bb * sstride;

    // B staging mapping: vec index v = t + 256*i (i<5, v<1216): col=v>>2, koff=(v&3)*8
    const int bcol0 = t >> 2, bkoff = (t & 3) * 8;

    f32x4 acc[2][10];
    #pragma unroll
    for (int rt = 0; rt < 2; rt++)
        #pragma unroll
        for (int ct = 0; ct < 10; ct++) acc[rt][ct] = (f32x4){0.f,0.f,0.f,0.f};

    float a8[8], s8[8];
    s16x8 bvec[5];

    // ---- prologue: load + store tile 0 ----
    {
        int k = sk;
        if (k + 8 <= KK) {
            float4 v0 = *(const float4*)(arow + k), v1 = *(const float4*)(arow + k + 4);
            a8[0]=v0.x; a8[1]=v0.y; a8[2]=v0.z; a8[3]=v0.w; a8[4]=v1.x; a8[5]=v1.y; a8[6]=v1.z; a8[7]=v1.w;
            float4 w0 = *(const float4*)(srow + k), w1 = *(const float4*)(srow + k + 4);
            s8[0]=w0.x; s8[1]=w0.y; s8[2]=w0.z; s8[3]=w0.w; s8[4]=w1.x; s8[5]=w1.y; s8[6]=w1.z; s8[7]=w1.w;
        } else {
            #pragma unroll
            for (int j = 0; j < 8; j++){ int kk = k + j; a8[j] = (kk < KK) ? arow[kk] : 0.f; s8[j] = (kk < KK) ? srow[kk] : 0.f; }
        }
        #pragma unroll
        for (int i = 0; i < 5; i++){
            int v = t + 256 * i;
            if (v < 1216) bvec[i] = *(const s16x8*)&Bt[(size_t)(v >> 2) * BPITCH + ((v & 3) * 8)];
        }
        s16x8 pv;
        #pragma unroll
        for (int j = 0; j < 8; j++) pv[j] = (short)f2bf(a8[j] * s8[j]);
        *(s16x8*)&As[0][sr * 40 + sk] = pv;
        #pragma unroll
        for (int i = 0; i < 5; i++){
            int v = t + 256 * i;
            if (v < 1216) *(s16x8*)&Bs[0][(v >> 2) * 36 + ((v & 3) * 8)] = bvec[i];
        }
    }
    __syncthreads();

    int cur = 0;
    for (int kt = 0; kt < NTILES; ++kt) {
        // issue next-tile global loads (stay in flight across MFMA phase)
        if (kt + 1 < NTILES) {
            int k = (kt + 1) * 32 + sk;
            if (k + 8 <= KK) {
                float4 v0 = *(const float4*)(arow + k), v1 = *(const float4*)(arow + k + 4);
                a8[0]=v0.x; a8[1]=v0.y; a8[2]=v0.z; a8[3]=v0.w; a8[4]=v1.x; a8[5]=v1.y; a8[6]=v1.z; a8[7]=v1.w;
                float4 w0 = *(const float4*)(srow + k), w1 = *(const float4*)(srow + k + 4);
                s8[0]=w0.x; s8[1]=w0.y; s8[2]=w0.z; s8[3]=w0.w; s8[4]=w1.x; s8[5]=w1.y; s8[6]=w1.z; s8[7]=w1.w;
            } else {
                #pragma unroll
                for (int j = 0; j < 8; j++){ int kk = k + j; a8[j] = (kk < KK) ? arow[kk] : 0.f; s8[j] = (kk < KK) ? srow[kk] : 0.f; }
            }
            int k0 = (kt + 1) * 32;
            #pragma unroll
            for (int i = 0; i < 5; i++){
                int v = t + 256 * i;
                if (v < 1216) bvec[i] = *(const s16x8*)&Bt[(size_t)(v >> 2) * BPITCH + k0 + ((v & 3) * 8)];
            }
        }
        // MFMA phase from buf[cur]
        s16x8 af0 = *(s16x8*)&As[cur][(wr * 32 + (lane & 15)) * 40 + (lane >> 4) * 8];
        s16x8 af1 = *(s16x8*)&As[cur][(wr * 32 + 16 + (lane & 15)) * 40 + (lane >> 4) * 8];
        #pragma unroll
        for (int ct = 0; ct < 10; ct++) {
            if (wc == 1 && ct == 9) continue;
            int col = wc * 160 + ct * 16 + (lane & 15);
            s16x8 bf = *(s16x8*)&Bs[cur][col * 36 + (lane >> 4) * 8];
            acc[0][ct] = __builtin_amdgcn_mfma_f32_16x16x32_bf16(af0, bf, acc[0][ct], 0, 0, 0);
            acc[1][ct] = __builtin_amdgcn_mfma_f32_16x16x32_bf16(af1, bf, acc[1][ct], 0, 0, 0);
        }
        // write next tile into the other buffer
        if (kt + 1 < NTILES) {
            s16x8 pv;
            #pragma unroll
            for (int j = 0; j < 8; j++) pv[j] = (short)f2bf(a8[j] * s8[j]);
            *(s16x8*)&As[cur ^ 1][sr * 40 + sk] = pv;
            #pragma unroll
            for (int i = 0; i < 5; i++){
                int v = t + 256 * i;
                if (v < 1216) *(s16x8*)&Bs[cur ^ 1][(v >> 2) * 36 + ((v & 3) * 8)] = bvec[i];
            }
        }
        __syncthreads();
        cur ^= 1;
    }

    // ---- epilogue: per-row sum of elu(C)*w ----
    float p[2][4];
    #pragma unroll
    for (int rt = 0; rt < 2; rt++)
        #pragma unroll
        for (int i = 0; i < 4; i++) p[rt][i] = 0.f;
    #pragma unroll
    for (int ct = 0; ct < 10; ct++) {
        if (wc == 1 && ct == 9) continue;
        int col = wc * 160 + ct * 16 + (lane & 15);
        float wv = wpad[col];
        #pragma unroll
        for (int rt = 0; rt < 2; rt++)
            #pragma unroll
            for (int i = 0; i < 4; i++)
                p[rt][i] += eluf(acc[rt][ct][i]) * wv;
    }
    #pragma unroll
    for (int m = 1; m <= 8; m <<= 1) {
        #pragma unroll
        for (int rt = 0; rt < 2; rt++)
            #pragma unroll
            for (int i = 0; i < 4; i++)
                p[rt][i] += __shfl_xor(p[rt][i], m);
    }
    if ((lane & 15) == 0) {
        int q = lane >> 4;
        #pragma unroll
        for (int rt = 0; rt < 2; rt++)
            #pragma unroll
            for (int i = 0; i < 4; i++)
                red[wr][wc][rt * 16 + q * 4 + i] = p[rt][i];
    }
    __syncthreads();
    if (t < 64) {
        int wrr = t >> 5, r = t & 31;
        out[rowBlock + wrr * 32 + r] = red[wrr][0][r] + red[wrr][1][r];
    }
}

__global__ __launch_bounds__(256, 2) void mfma_node_k(
    const float* __restrict__ A, const unsigned short* __restrict__ Bt,
    const float* __restrict__ S, const int* __restrict__ rowb,
    const float* __restrict__ wpad, float* __restrict__ out)
{
    mfma_score_impl<2400, 2400, 75>(A, 2400, Bt, S, 2400, rowb, wpad, out);
}

__global__ __launch_bounds__(256, 2) void mfma_edge_k(
    const float* __restrict__ A, const unsigned short* __restrict__ Bt,
    const float* __restrict__ S, const int* __restrict__ rowb,
    const float* __restrict__ wpad, float* __restrict__ out)
{
    mfma_score_impl<300, 320, 10>(A, 300, Bt, S, NI * 300, rowb, wpad, out);
}

__global__ void build_bt_k(const float* __restrict__ B, int K, int N, int bpitch,
                           unsigned short* __restrict__ Bt)
{
    int idx = blockIdx.x * 256 + threadIdx.x;
    if (idx >= 304 * bpitch) return;
    int col = idx / bpitch, k = idx - col * bpitch;
    float v = (col < N && k < K) ? B[(size_t)k * N + col] : 0.f;
    Bt[idx] = f2bf(v);
}

__global__ void wpad_k(const float* __restrict__ wn, const float* __restrict__ wr,
                       float* __restrict__ wnp, float* __restrict__ wrp)
{
    int i = threadIdx.x;
    if (i < 304) { wnp[i] = (i < 300) ? wn[i] : 0.f; wrp[i] = (i < 300) ? wr[i] : 0.f; }
}

// ---------------------------------------------------------------------------
// Parallel f32 GEMM: 64x64 tile, 256 threads, 4x4 per thread, optional split-K.
// ---------------------------------------------------------------------------
template<bool BT, int EPI>
__global__ __launch_bounds__(256) void gemm2_k(
    const float* __restrict__ A, int lda, int M, int K, int kChunk,
    const float* __restrict__ Bm, int ldb, int N,
    float* __restrict__ C)
{
    __shared__ float As[16][68];
    __shared__ float Bs[16][68];
    const int t = threadIdx.x;
    const int rowBlock = blockIdx.x * 64, colBase = blockIdx.y * 64;
    const int k0 = blockIdx.z * kChunk;
    const int kend = min(K, k0 + kChunk);

    float acc[4][4] = {{0.f}};
    const int am = t >> 2, ak4 = (t & 3) * 4;
    const int tx = t & 15, ty = t >> 4;

    for (int kt = k0; kt < kend; kt += 16) {
        {
            int gr = rowBlock + am;
            #pragma unroll
            for (int j = 0; j < 4; j++) {
                int gk = kt + ak4 + j;
                As[ak4 + j][am] = (gr < M && gk < kend) ? A[(size_t)gr * lda + gk] : 0.f;
            }
        }
        if (!BT) {
            int bk = t >> 4, bcc = (t & 15) * 4;
            int gk = kt + bk;
            #pragma unroll
            for (int j = 0; j < 4; j++) {
                int gc = colBase + bcc + j;
                Bs[bk][bcc + j] = (gk < kend && gc < N) ? Bm[(size_t)gk * ldb + gc] : 0.f;
            }
        } else {
            int bc = t >> 2, bk4 = (t & 3) * 4;
            int gc = colBase + bc;
            #pragma unroll
            for (int j = 0; j < 4; j++) {
                int gk = kt + bk4 + j;
                Bs[bk4 + j][bc] = (gk < kend && gc < N) ? Bm[(size_t)gc * ldb + gk] : 0.f;
            }
        }
        __syncthreads();
        #pragma unroll
        for (int kk = 0; kk < 16; kk++) {
            float4 a4 = *(float4*)&As[kk][ty * 4];
            float4 b4 = *(float4*)&Bs[kk][tx * 4];
            float av[4] = {a4.x, a4.y, a4.z, a4.w};
            float bv[4] = {b4.x, b4.y, b4.z, b4.w};
            #pragma unroll
            for (int r = 0; r < 4; r++)
                #pragma unroll
                for (int c = 0; c < 4; c++)
                    acc[r][c] = fmaf(av[r], bv[c], acc[r][c]);
        }
        __syncthreads();
    }

    #pragma unroll
    for (int r = 0; r < 4; r++) {
        int row = rowBlock + ty * 4 + r;
        if (row >= M) continue;
        #pragma unroll
        for (int c = 0; c < 4; c++) {
            int col = colBase + tx * 4 + c;
            if (col >= N) continue;
            if (EPI == 0) C[(size_t)row * N + col] = acc[r][c];
            else atomicAdd(&C[(size_t)row * N + col], acc[r][c]);
        }
    }
}

template<int EPI>
__global__ void mm_naive_bt_k(const float* __restrict__ A, int lda, int M, int K,
                              const float* __restrict__ Bm, int N,
                              const float* __restrict__ bias,
                              float* __restrict__ Cf)
{
    int idx = blockIdx.x * 256 + threadIdx.x;
    if (idx >= M * N) return;
    int m = idx / N;
    int j = idx - m * N;
    const float* arow = A + (size_t)m * lda;
    const float* brow = Bm + (size_t)j * K;
    float s = 0.f;
    for (int k = 0; k < K; k++) s += arow[k] * brow[k];
    if (EPI == 0) Cf[idx] = s;
    else if (EPI == 2) Cf[idx] = eluf(s + bias[j]);
    else Cf[idx] = s + bias[j];
}

__global__ void transpose_k(const float* __restrict__ src, int R, int C,
                            float* __restrict__ dst)
{
    int idx = blockIdx.x * 256 + threadIdx.x;
    if (idx >= R * C) return;
    int r = idx / C, c = idx - r * C;
    dst[(size_t)c * R + r] = src[idx];
}

// Pack lstm Whh [1200][300] -> bf16 k-major WT[k][1200]
__global__ void pack_whhT_k(const float* __restrict__ W, unsigned short* __restrict__ WT)
{
    int idx = blockIdx.x * 256 + threadIdx.x;
    if (idx >= 300 * 1200) return;
    int k = idx / 1200, r = idx - k * 1200;
    WT[idx] = f2bf(W[(size_t)r * 300 + k]);
}

// ---------------------------------------------------------------------------
__global__ void vocab_build_k(const float* __restrict__ cv, const float* __restrict__ td,
                              float* __restrict__ ve)
{
    int idx = blockIdx.x * 256 + threadIdx.x;
    if (idx < 2001 * 300) ve[idx] = (idx < 2000 * 300) ? cv[idx] : td[idx - 2000 * 300];
}

__global__ void softmax_rows_k(float* __restrict__ X, int nc)
{
    int row = blockIdx.x, t = threadIdx.x;
    __shared__ float red[256];
    size_t base = (size_t)row * nc;
    float m = -3.4e38f;
    for (int i = t; i < nc; i += 256) m = fmaxf(m, X[base + i]);
    red[t] = m; __syncthreads();
    for (int s = 128; s > 0; s >>= 1){ if (t < s) red[t] = fmaxf(red[t], red[t+s]); __syncthreads(); }
    float mx = red[0]; __syncthreads();
    float sm = 0.f;
    for (int i = t; i < nc; i += 256){ float e = expf(X[base + i] - mx); X[base + i] = e; sm += e; }
    red[t] = sm; __syncthreads();
    for (int s = 128; s > 0; s >>= 1){ if (t < s) red[t] += red[t+s]; __syncthreads(); }
    float inv = 1.f / red[0];
    for (int i = t; i < nc; i += 256) X[base + i] *= inv;
}

__global__ void tagged_add_k(const float* __restrict__ sim, const float* __restrict__ q,
                             float* __restrict__ tg)
{
    int idx = blockIdx.x * 256 + threadIdx.x;
    if (idx >= 960 * 300) return;
    int row = idx / 300;
    tg[idx] += sim[(size_t)row * 2001 + 2000] * q[idx];
}

// Fast persistent LSTM: 1 block/batch, 640 threads (10 waves).
// Threads 0..599 each own 2 gate rows (2t, 2t+1); threads 0..299 own hid t (c,h).
// WT: bf16 [300][1200] k-major.
__global__ __launch_bounds__(640) void lstm_fast_k(
    const float* __restrict__ xW, const unsigned short* __restrict__ WT,
    const float* __restrict__ bih, const float* __restrict__ bhh,
    const int* __restrict__ lengths, float* __restrict__ encoded)
{
    __shared__ float hs[300];
    __shared__ float gs[1200];
    const int b = blockIdx.x, t = threadIdx.x;
    const int len = lengths[b];
    const bool ga = t < 600;
    const bool ha = t < 300;
    float bs0 = 0.f, bs1 = 0.f;
    if (ga) { bs0 = bih[2*t] + bhh[2*t]; bs1 = bih[2*t+1] + bhh[2*t+1]; }
    if (ha) hs[t] = 0.f;
    float c = 0.f, h = 0.f;
    __syncthreads();
    const float* xb = xW + (size_t)b * Ll * 1200;
    for (int st = 0; st < len; ++st) {
        if (ga) {
            float d0 = 0.f, d1 = 0.f;
            const unsigned short* wp = WT + 2 * t;
            #pragma unroll 4
            for (int k = 0; k < 300; k++) {
                float hk = hs[k];
                unsigned wv = *(const unsigned*)(wp + (size_t)k * 1200);
                d0 = fmaf(hk, __uint_as_float(wv << 16), d0);
                d1 = fmaf(hk, __uint_as_float(wv & 0xFFFF0000u), d1);
            }
            const float* xr = xb + st * 1200;
            gs[2*t]   = xr[2*t]   + bs0 + d0;
            gs[2*t+1] = xr[2*t+1] + bs1 + d1;
        }
        __syncthreads();
        if (ha) {
            float i_ = sigf(gs[t]);
            float f_ = sigf(gs[300 + t]);
            float g_ = tanhf(gs[600 + t]);
            float o_ = sigf(gs[900 + t]);
            c = f_ * c + i_ * g_;
            h = o_ * tanhf(c);
            hs[t] = h;
        }
        __syncthreads();
    }
    if (ha) encoded[b * 300 + t] = h;
}

// Persistent RNN decoder (unchanged)
__global__ __launch_bounds__(320) void rnn_all_k(
    const float* __restrict__ enc, const float* __restrict__ WihT,
    const float* __restrict__ WhhT,
    const float* __restrict__ bih, const float* __restrict__ bhh,
    float* __restrict__ hidden)
{
    __shared__ float es[304];
    __shared__ float hs[304];
    const int b = blockIdx.x, i = threadIdx.x;
    const bool act = i < 300;
    if (act) { es[i] = enc[b * 300 + i]; hs[i] = 0.f; }
    __syncthreads();
    float ex = 0.f;
    if (act) {
        #pragma unroll 4
        for (int k = 0; k < 300; k++)
            ex = fmaf(es[k], WihT[(size_t)k * 300 + i], ex);
        ex += bih[i] + bhh[i];
    }
    for (int it = 0; it < NI; it++) {
        __syncthreads();
        float d = 0.f;
        if (act) {
            #pragma unroll 4
            for (int k = 0; k < 300; k++)
                d = fmaf(hs[k], WhhT[(size_t)k * 300 + i], d);
        }
        float v = fmaxf(ex + d, 0.f);
        __syncthreads();
        if (act) { hs[i] = v; hidden[((size_t)b * NI + it) * 300 + i] = v; }
    }
}

__global__ __launch_bounds__(256) void scores_instr_k(
    const float* __restrict__ hidden, const float* __restrict__ tagged,
    const int* __restrict__ lengths, float* __restrict__ instr)
{
    __shared__ float sc[4][32];
    int wv = threadIdx.x >> 6;
    int wid = blockIdx.x * 4 + wv;
    int lane = threadIdx.x & 63;
    int b = wid / NI;
    const float* hr = hidden + (size_t)wid * Hh;
    float hv[5];
    #pragma unroll
    for (int p = 0; p < 5; p++){ int k = lane + p * 64; hv[p] = (k < Hh) ? hr[k] : 0.f; }
    int len = lengths[b];
    for (int l = 0; l < Ll; l++){
        const float* trw = tagged + ((size_t)b * Ll + l) * Hh;
        float s = 0.f;
        #pragma unroll
        for (int p = 0; p < 5; p++){ int k = lane + p * 64; if (k < Hh) s += hv[p] * trw[k]; }
        s = wave_sum(s);
        if (lane == 0) sc[wv][l] = s;
    }
    __syncthreads();
    float mx = -3.4e38f;
    for (int l = 0; l < len; l++) mx = fmaxf(mx, sc[wv][l]);
    float sum = 0.f;
    for (int l = 0; l < len; l++) sum += expf(sc[wv][l] - mx);
    float inv = 1.f / sum;
    float a[5] = {0.f,0.f,0.f,0.f,0.f};
    for (int l = 0; l < len; l++){
        float pl = expf(sc[wv][l] - mx) * inv;
        const float* trw = tagged + ((size_t)b * Ll + l) * Hh;
        #pragma unroll
        for (int p = 0; p < 5; p++){ int k = lane + p * 64; if (k < Hh) a[p] += pl * trw[k]; }
    }
    #pragma unroll
    for (int p = 0; p < 5; p++){ int k = lane + p * 64; if (k < Hh) instr[(size_t)wid * Hh + k] = a[p]; }
}

__global__ __launch_bounds__(256) void prop_softmax_k(
    const float* __restrict__ instr, int ii, const float* __restrict__ pemb,
    float* __restrict__ psim, float* __restrict__ rsim)
{
    int wid = blockIdx.x * 4 + (threadIdx.x >> 6);
    int lane = threadIdx.x & 63;
    const float* ir = instr + ((size_t)wid * NI + ii) * Hh;
    float iv[5];
    #pragma unroll
    for (int p = 0; p < 5; p++){ int k = lane + p * 64; iv[p] = (k < Hh) ? ir[k] : 0.f; }
    float e[9];
    #pragma unroll
    for (int j = 0; j < 9; j++){
        const float* pr = pemb + j * Hh;
        float s = 0.f;
        #pragma unroll
        for (int p = 0; p < 5; p++){ int k = lane + p * 64; if (k < Hh) s += iv[p] * pr[k]; }
        e[j] = wave_sum(s);
    }
    if (lane == 0){
        float mx = e[0];
        #pragma unroll
        for (int j = 1; j < 9; j++) mx = fmaxf(mx, e[j]);
        float sum = 0.f;
        #pragma unroll
        for (int j = 0; j < 9; j++){ e[j] = expf(e[j] - mx); sum += e[j]; }
        float inv = 1.f / sum;
        #pragma unroll
        for (int p = 0; p < 8; p++) psim[wid * 8 + p] = e[p] * inv;
        rsim[wid] = e[8] * inv;
    }
}

__global__ void iscale_k(const float* __restrict__ instr, int step,
                         const float* __restrict__ psim, float* __restrict__ iscale)
{
    int idx = blockIdx.x * 256 + threadIdx.x;
    if (idx >= Bb * 2400) return;
    int b = idx / 2400; int k = idx - b * 2400;
    int p = k / 300;    int h = k - p * 300;
    iscale[idx] = instr[((size_t)b * NI + step) * Hh + h] * psim[b * 8 + p];
}

__global__ void count_k(const int* __restrict__ ni, int* __restrict__ cnt)
{
    int n = blockIdx.x * 256 + threadIdx.x;
    if (n < Nn) atomicAdd(&cnt[ni[n]], 1);
}
__global__ void dist_init_k(const int* __restrict__ ni, const int* __restrict__ cnt,
                            float* __restrict__ dist)
{
    int n = blockIdx.x * 256 + threadIdx.x;
    if (n < Nn) dist[n] = 1.f / (float)cnt[ni[n]];
}

__global__ void edge_msg_k(const int* __restrict__ ei, const float* __restrict__ es,
                           const float* __restrict__ dist, float* __restrict__ msgdot)
{
    int e = blockIdx.x * 256 + threadIdx.x;
    if (e < Ee){
        int s = ei[e];
        int d = ei[Ee + e];
        atomicAdd(&msgdot[d], dist[s] * es[e]);
    }
}

__global__ __launch_bounds__(256) void seg_update_k(
    const float* __restrict__ nscore, const float* __restrict__ msgdot,
    const float* __restrict__ rsim, float* __restrict__ dist)
{
    int b = blockIdx.x, t = threadIdx.x;
    __shared__ float red[256];
    int n0 = b * NPG;
    float a1 = nscore[n0 + t], a2 = nscore[n0 + 256 + t];
    float m1 = msgdot[n0 + t], m2 = msgdot[n0 + 256 + t];

    red[t] = fmaxf(a1, a2); __syncthreads();
    for (int s = 128; s > 0; s >>= 1){ if (t < s) red[t] = fmaxf(red[t], red[t+s]); __syncthreads(); }
    float mN = red[0]; __syncthreads();
    float e1 = expf(a1 - mN), e2 = expf(a2 - mN);
    red[t] = e1 + e2; __syncthreads();
    for (int s = 128; s > 0; s >>= 1){ if (t < s) red[t] += red[t+s]; __syncthreads(); }
    float sN = red[0]; __syncthreads();

    red[t] = fmaxf(m1, m2); __syncthreads();
    for (int s = 128; s > 0; s >>= 1){ if (t < s) red[t] = fmaxf(red[t], red[t+s]); __syncthreads(); }
    float mM = red[0]; __syncthreads();
    float f1 = expf(m1 - mM), f2 = expf(m2 - mM);
    red[t] = f1 + f2; __syncthreads();
    for (int s = 128; s > 0; s >>= 1){ if (t < s) red[t] += red[t+s]; __syncthreads(); }
    float sM = red[0];

    float rs = rsim[b];
    dist[n0 + t]       = rs * (f1 / sM) + (1.f - rs) * (e1 / sN);
    dist[n0 + 256 + t] = rs * (f2 / sM) + (1.f - rs) * (e2 / sN);
}

__global__ __launch_bounds__(320) void final_agg_k(
    const float* __restrict__ psim, const float* __restrict__ dist,
    const float* __restrict__ na, float* __restrict__ agg)
{
    int chunk = blockIdx.x;
    int b = blockIdx.y;
    int h = threadIdx.x;
    if (h >= Hh) return;
    float ps[8];
    #pragma unroll
    for (int p = 0; p < 8; p++) ps[p] = psim[b * 8 + p];
    float acc = 0.f;
    for (int i = 0; i < 32; i++){
        int n = b * NPG + chunk * 32 + i;
        const float* row = na + (size_t)n * Pp * Hh;
        float wsum = 0.f;
        #pragma unroll
        for (int p = 0; p < 8; p++) wsum += ps[p] * row[p * Hh + h];
        acc += dist[n] * wsum;
    }
    atomicAdd(&agg[b * Hh + h], acc);
}

__global__ void feats_k(const float* __restrict__ enc, const float* __restrict__ agg,
                        float* __restrict__ feats)
{
    int idx = blockIdx.x * 256 + threadIdx.x;
    if (idx >= Bb * 600) return;
    int b = idx / 600, j = idx - b * 600;
    feats[idx] = (j < 300) ? enc[b * 300 + j] : agg[b * 300 + (j - 300)];
}

// ---------------------------------------------------------------------------
extern "C" void kernel_launch(void* const* d_in, const int* in_sizes, int n_in,
                              void* d_out, int out_size, void* d_ws, size_t ws_size,
                              hipStream_t stream)
{
    const float* questions      = (const float*)d_in[0];
    const int*   lengths        = (const int*)  d_in[1];
    const int*   node_indices   = (const int*)  d_in[2];
    const int*   edge_indices   = (const int*)  d_in[3];
    const int*   edge_batch     = (const int*)  d_in[4];
    const float* node_attrs     = (const float*)d_in[5];
    const float* edge_attrs     = (const float*)d_in[6];
    const float* concept_vocab  = (const float*)d_in[7];
    const float* prop_emb       = (const float*)d_in[8];
    const float* tagger_default = (const float*)d_in[9];
    const float* tagger_weight  = (const float*)d_in[10];
    const float* lstm_Wih       = (const float*)d_in[11];
    const float* lstm_Whh       = (const float*)d_in[12];
    const float* lstm_bih       = (const float*)d_in[13];
    const float* lstm_bhh       = (const float*)d_in[14];
    const float* rnn_Wih        = (const float*)d_in[15];
    const float* rnn_Whh        = (const float*)d_in[16];
    const float* rnn_bih        = (const float*)d_in[17];
    const float* rnn_bhh        = (const float*)d_in[18];
    const float* Wnp            = (const float*)d_in[19];
    const float* Wedge          = (const float*)d_in[20];
    const float* w_nscore       = (const float*)d_in[21];
    const float* w_rscore       = (const float*)d_in[22];
    const float* fc1_W          = (const float*)d_in[23];
    const float* fc1_b          = (const float*)d_in[24];
    const float* fc2_W          = (const float*)d_in[25];
    const float* fc2_b          = (const float*)d_in[26];
    float* outf = (float*)d_out;

    float* ws = (float*)d_ws;
    size_t off = 0;
    auto alloc = [&](size_t n){ size_t r = off; off += (n + 63) & ~(size_t)63; return r; };
    size_t o_vocab  = alloc(2001 * 300);
    size_t o_q2     = alloc(960 * 300);
    size_t o_sim    = alloc((size_t)960 * 2001);
    size_t o_tagged = alloc(960 * 300);
    size_t o_xw     = alloc((size_t)960 * 1200);
    size_t o_enc    = alloc(9600);
    size_t o_hidden = alloc(48000);
    size_t o_instr  = alloc(48000);
    size_t o_psim   = alloc(256);
    size_t o_rsim   = alloc(64);
    size_t o_iscale = alloc((size_t)Bb * 2400);
    size_t o_nscore = alloc(Nn);
    size_t o_es     = alloc(Ee);
    size_t o_msgdot = alloc(Nn);
    size_t o_dist   = alloc(Nn);
    size_t o_cnt    = alloc(64);
    size_t o_agg    = alloc(9600);
    size_t o_feats  = alloc(19200);
    size_t o_z      = alloc(19200);
    size_t o_btn    = alloc((size_t)304 * 2400 / 2);   // Wnp^T bf16
    size_t o_bte    = alloc((size_t)304 * 320 / 2);    // Wedge^T bf16
    size_t o_wn     = alloc(304);
    size_t o_wr     = alloc(304);
    size_t o_wlstm  = alloc(180000);   // lstm Whh bf16 k-major [300][1200]
    size_t o_rwhhT  = alloc(90000);
    size_t o_rwihT  = alloc(90000);

    unsigned short* btn = (unsigned short*)(ws + o_btn);
    unsigned short* bte = (unsigned short*)(ws + o_bte);
    unsigned short* wlstm = (unsigned short*)(ws + o_wlstm);

    // ---- one-time conversions ----
    build_bt_k<<<(304*2400 + 255)/256, 256, 0, stream>>>(Wnp, 2400, 300, 2400, btn);
    build_bt_k<<<(304*320 + 255)/256, 256, 0, stream>>>(Wedge, 300, 300, 320, bte);
    wpad_k<<<1, 320, 0, stream>>>(w_nscore, w_rscore, ws + o_wn, ws + o_wr);
    pack_whhT_k<<<(300*1200 + 255)/256, 256, 0, stream>>>(lstm_Whh, wlstm);
    transpose_k<<<(300*300 + 255)/256, 256, 0, stream>>>(rnn_Whh, 300, 300, ws + o_rwhhT);
    transpose_k<<<(300*300 + 255)/256, 256, 0, stream>>>(rnn_Wih, 300, 300, ws + o_rwihT);
    vocab_build_k<<<(2001*300 + 255)/256, 256, 0, stream>>>(concept_vocab, tagger_default, ws + o_vocab);

    // ---- tagger chain ----
    gemm2_k<false,0><<<dim3(15,5,1), 256, 0, stream>>>(
        questions, 300, 960, 300, 300, tagger_weight, 300, 300, ws + o_q2);
    gemm2_k<true,0><<<dim3(15,32,1), 256, 0, stream>>>(
        ws + o_q2, 300, 960, 300, 300, ws + o_vocab, 300, 2001, ws + o_sim);
    softmax_rows_k<<<960, 256, 0, stream>>>(ws + o_sim, 2001);
    hipMemsetAsync(ws + o_tagged, 0, 960 * 300 * sizeof(float), stream);
    gemm2_k<false,1><<<dim3(15,5,4), 256, 0, stream>>>(
        ws + o_sim, 2001, 960, 2000, 500, concept_vocab, 300, 300, ws + o_tagged);
    tagged_add_k<<<1125, 256, 0, stream>>>(ws + o_sim, questions, ws + o_tagged);

    // ---- LSTM ----
    gemm2_k<true,0><<<dim3(15,19,1), 256, 0, stream>>>(
        ws + o_tagged, 300, 960, 300, 300, lstm_Wih, 300, 1200, ws + o_xw);
    lstm_fast_k<<<Bb, 640, 0, stream>>>(ws + o_xw, wlstm, lstm_bih, lstm_bhh,
                                        lengths, ws + o_enc);

    // ---- RNN instruction decoder + instructions ----
    rnn_all_k<<<Bb, 320, 0, stream>>>(ws + o_enc, ws + o_rwihT, ws + o_rwhhT,
                                      rnn_bih, rnn_bhh, ws + o_hidden);
    scores_instr_k<<<40, 256, 0, stream>>>(ws + o_hidden, ws + o_tagged, lengths, ws + o_instr);

    // ---- distribution init ----
    hipMemsetAsync(ws + o_cnt, 0, 32 * sizeof(int), stream);
    count_k<<<64, 256, 0, stream>>>(node_indices, (int*)(ws + o_cnt));
    dist_init_k<<<64, 256, 0, stream>>>(node_indices, (int*)(ws + o_cnt), ws + o_dist);

    // ---- 4 message-passing steps ----
    for (int step = 0; step < 4; step++){
        prop_softmax_k<<<8, 256, 0, stream>>>(ws + o_instr, step, prop_emb, ws + o_psim, ws + o_rsim);
        iscale_k<<<300, 256, 0, stream>>>(ws + o_instr, step, ws + o_psim, ws + o_iscale);
        mfma_node_k<<<Nn/64, 256, 0, stream>>>(
            node_attrs, btn, ws + o_iscale, node_indices, ws + o_wn, ws + o_nscore);
        mfma_edge_k<<<Ee/64, 256, 0, stream>>>(
            edge_attrs, bte, ws + o_instr + step * 300, edge_batch, ws + o_wr, ws + o_es);
        hipMemsetAsync(ws + o_msgdot, 0, Nn * sizeof(float), stream);
        edge_msg_k<<<512, 256, 0, stream>>>(edge_indices, ws + o_es, ws + o_dist, ws + o_msgdot);
        seg_update_k<<<32, 256, 0, stream>>>(ws + o_nscore, ws + o_msgdot, ws + o_rsim, ws + o_dist);
    }

    // ---- final aggregation + FCs ----
    prop_softmax_k<<<8, 256, 0, stream>>>(ws + o_instr, 4, prop_emb, ws + o_psim, ws + o_rsim);
    hipMemsetAsync(ws + o_agg, 0, 9600 * sizeof(float), stream);
    final_agg_k<<<dim3(16,32), 320, 0, stream>>>(ws + o_psim, ws + o_dist, node_attrs, ws + o_agg);
    feats_k<<<75, 256, 0, stream>>>(ws + o_enc, ws + o_agg, ws + o_feats);
    mm_naive_bt_k<2><<<75, 256, 0, stream>>>(
        ws + o_feats, 600, 32, 600, fc1_W, 600, fc1_b, ws + o_z);
    mm_naive_bt_k<3><<<(32*1845 + 255)/256, 256, 0, stream>>>(
        ws + o_z, 600, 32, 600, fc2_W, 1845, fc2_b, outf);
}